// Round 12
// baseline (430.691 us; speedup 1.0000x reference)
//
#include <hip/hip_runtime.h>

using u16 = unsigned short;
using u32 = unsigned int;

constexpr int Bn   = 256;
constexpr int Dd   = 1280;
constexpr int Cc   = 64;
constexpr int WINc = 14;
constexpr int NHc  = 8;
constexpr int Ac   = 49;
constexpr int Nc   = WINc * WINc;   // 196
constexpr int HDc  = Cc / NHc;      // 8
constexpr int B3c  = 3 * Bn;        // 768
constexpr int CNc  = Cc * Nc;       // 12544

typedef __attribute__((ext_vector_type(8))) short v8s;   // 8 bf16 = 4 VGPRs
typedef __attribute__((ext_vector_type(4))) float v4f;
typedef __attribute__((ext_vector_type(2))) float v2f;   // packed fp32 (v_pk_*)

// bf16 helpers: inputs fp32, workspace intermediates bf16, OUTPUT fp32.
__device__ __forceinline__ float bflo(u32 u){ union{u32 x; float f;} c; c.x = u << 16; return c.f; }
__device__ __forceinline__ float bfhi(u32 u){ union{u32 x; float f;} c; c.x = u & 0xffff0000u; return c.f; }
__device__ __forceinline__ float bfs(u16 h){ union{u32 x; float f;} c; c.x = ((u32)h) << 16; return c.f; }
__device__ __forceinline__ u16 f2bb(float f){
  u32 u = __float_as_uint(f);
  u32 r = (u + 0x7fffu + ((u >> 16) & 1u)) >> 16;
  return (u16)r;
}
__device__ __forceinline__ void unpack8(uint4 u, float* dst){
  dst[0]=bflo(u.x); dst[1]=bfhi(u.x); dst[2]=bflo(u.y); dst[3]=bfhi(u.y);
  dst[4]=bflo(u.z); dst[5]=bfhi(u.z); dst[6]=bflo(u.w); dst[7]=bfhi(u.w);
}
__device__ __forceinline__ uint4 pack8(const float* s){
  uint4 r;
  r.x = (u32)f2bb(s[0]) | ((u32)f2bb(s[1]) << 16);
  r.y = (u32)f2bb(s[2]) | ((u32)f2bb(s[3]) << 16);
  r.z = (u32)f2bb(s[4]) | ((u32)f2bb(s[5]) << 16);
  r.w = (u32)f2bb(s[6]) | ((u32)f2bb(s[7]) << 16);
  return r;
}

// async global->LDS, 16B per lane; LDS dest = wave-uniform base + lane*16
__device__ __forceinline__ void gl_lds16(const u16* g, u16* l){
  __builtin_amdgcn_global_load_lds(
      (const __attribute__((address_space(1))) unsigned int*)g,
      (__attribute__((address_space(3))) unsigned int*)l,
      16, 0, 0);
}

// ---------------------------------------------------------------------------
// One-time fp32->bf16 conversion of W_embed, X, W_adj, W1, W2,
// PLUS (fused) position-bias precompute. Biases pre-scaled by log2(e) so
// attn uses exp2 (one fma + v_exp per score) — numerics validated in R3.
// ---------------------------------------------------------------------------
constexpr int WeN   = 12544 * 1280;   // 16,056,320
constexpr int XN    = 768 * 1280;     //    983,040
constexpr int WadjN = 256 * CNc;      //  3,211,264
constexpr int W1N   = 256 * 1280;     //    327,680
constexpr int W2N   = 128 * 256;      //     32,768
constexpr int CONVB = (WeN + XN + WadjN + W1N + W2N) / (256*8);   // 10064
constexpr int BIASB = (2 * NHc * Ac * Nc + 255) / 256;            // 601
__global__ __launch_bounds__(256) void conv_bias_kernel(const float* __restrict__ We,
                                                        const float* __restrict__ X,
                                                        const float* __restrict__ Wadj,
                                                        const float* __restrict__ W1,
                                                        const float* __restrict__ W2,
                                                        u16* __restrict__ WeB,
                                                        u16* __restrict__ XB,
                                                        u16* __restrict__ WadjB,
                                                        u16* __restrict__ W1B,
                                                        u16* __restrict__ W2B,
                                                        const float* __restrict__ an, const float* __restrict__ na,
                                                        const float* __restrict__ ah, const float* __restrict__ aw,
                                                        const float* __restrict__ ha, const float* __restrict__ wa,
                                                        float* __restrict__ pb, float* __restrict__ ab)
{
  if (blockIdx.x >= CONVB) {
    // ---- bias path (math identical; output scaled by LOG2E) ----
    constexpr float LOG2E = 1.4426950408889634f;
    const int total = NHc * Ac * Nc;   // 76832
    int idx = (blockIdx.x - CONVB) * 256 + threadIdx.x;
    if (idx >= 2 * total) return;
    const bool isab = idx >= total;
    const int r = isab ? idx - total : idx;
    const int h = r / (Ac * Nc);
    const int r2 = r % (Ac * Nc);
    int a, n;
    if (isab) { n = r2 / Ac; a = r2 % Ac; } else { a = r2 / Nc; n = r2 % Nc; }
    const int y = n / WINc, x = n % WINc;
    float sy = fminf(fmaxf(0.5f * y - 0.25f, 0.f), 6.f);
    float sx = fminf(fmaxf(0.5f * x - 0.25f, 0.f), 6.f);
    const int y0 = (int)sy, x0 = (int)sx;
    const float wy = sy - y0, wx = sx - x0;
    const int y1 = (y0 + 1 < 6) ? y0 + 1 : 6;
    const int x1 = (x0 + 1 < 6) ? x0 + 1 : 6;
    const float* src = (isab ? na : an) + (h * Ac + a) * 49;
    const float v00 = src[y0*7 + x0], v01 = src[y0*7 + x1];
    const float v10 = src[y1*7 + x0], v11 = src[y1*7 + x1];
    const float bi = (1.f - wy) * ((1.f - wx) * v00 + wx * v01)
                   + wy * ((1.f - wx) * v10 + wx * v11);
    if (!isab) pb[((size_t)h*Nc + n)*Ac + a] = (bi + ah[(h*Ac + a)*WINc + y] + aw[(h*Ac + a)*WINc + x]) * LOG2E;
    else       ab[((size_t)h*Ac + a)*Nc + n] = (bi + ha[(h*WINc + y)*Ac + a] + wa[(h*WINc + x)*Ac + a]) * LOG2E;
    return;
  }
  // ---- conv path ----
  const size_t idx = ((size_t)blockIdx.x * 256 + threadIdx.x) * 8;
  const float* src; u16* dst;
  if (idx < (size_t)WeN)                          { src = We + idx;                         dst = WeB + idx; }
  else if (idx < (size_t)WeN + XN)                { src = X + (idx - WeN);                  dst = XB + (idx - WeN); }
  else if (idx < (size_t)WeN + XN + WadjN)        { src = Wadj + (idx - WeN - XN);          dst = WadjB + (idx - WeN - XN); }
  else if (idx < (size_t)WeN + XN + WadjN + W1N)  { src = W1 + (idx - WeN - XN - WadjN);    dst = W1B + (idx - WeN - XN - WadjN); }
  else                                            { src = W2 + (idx - WeN - XN - WadjN - W1N); dst = W2B + (idx - WeN - XN - WadjN - W1N); }
  float v[8];
  *reinterpret_cast<float4*>(&v[0]) = *reinterpret_cast<const float4*>(src);
  *reinterpret_cast<float4*>(&v[4]) = *reinterpret_cast<const float4*>(src + 4);
  *reinterpret_cast<uint4*>(dst) = pack8(v);
}

// ---------------------------------------------------------------------------
// MERGED embed + mlp1 GEMM (same K=1280, same A=XB): blocks x<98 compute
// embed (B=WeB, N=12544, no tanh); x>=98 compute mlp1 (B=W1B, N=256, tanh).
// m97-style global_load_lds staging, 128x128 tile, 2-barrier K loop.
// Branch is wave-uniform per block. Saves one serial launch.
// ---------------------------------------------------------------------------
__global__ __launch_bounds__(256) void gemm_embed_mlp1(const u16* __restrict__ XB,
                                                       const u16* __restrict__ WeB,
                                                       const u16* __restrict__ W1B,
                                                       const float* __restrict__ be,
                                                       const float* __restrict__ b1,
                                                       u16* __restrict__ xt,
                                                       u16* __restrict__ H)
{
  constexpr int KK = Dd;
  __shared__ u16 As[128 * 32];
  __shared__ u16 Bs[128 * 32];
  const int t = threadIdx.x;
  const bool mlp = blockIdx.x >= 98;
  const int n0 = (mlp ? (blockIdx.x - 98) : blockIdx.x) * 128;
  const int m0 = blockIdx.y * 128;
  const u16* Bmat = mlp ? W1B : WeB;
  const float* bias = mlp ? b1 : be;
  u16* Cmat = mlp ? H : xt;
  const int NN = mlp ? 256 : CNc;
  const int wave = t >> 6, lane = t & 63;
  const int wm = wave >> 1, wn = wave & 1;
  const int mi = lane & 15, quad = lane >> 4;

  v4f acc[4][4];
  #pragma unroll
  for (int a = 0; a < 4; ++a)
    #pragma unroll
    for (int b = 0; b < 4; ++b) acc[a][b] = (v4f){0.f, 0.f, 0.f, 0.f};

  const int rs = wave*32 + (lane >> 2);
  const int cs = (lane & 3) * 8;
  const u16* ga0 = XB + (size_t)(m0 + rs) * KK + cs;
  const u16* ga1 = XB + (size_t)(m0 + rs + 16) * KK + cs;
  const u16* gb0 = Bmat + (size_t)(n0 + rs) * KK + cs;
  const u16* gb1 = Bmat + (size_t)(n0 + rs + 16) * KK + cs;
  u16* la0 = &As[(wave*32)      * 32];
  u16* la1 = &As[(wave*32 + 16) * 32];
  u16* lb0 = &Bs[(wave*32)      * 32];
  u16* lb1 = &Bs[(wave*32 + 16) * 32];

  for (int kt = 0; kt < KK; kt += 32) {
    gl_lds16(ga0 + kt, la0);
    gl_lds16(ga1 + kt, la1);
    gl_lds16(gb0 + kt, lb0);
    gl_lds16(gb1 + kt, lb1);
    __syncthreads();

    v8s af[4], bf[4];
    #pragma unroll
    for (int mt = 0; mt < 4; ++mt)
      af[mt] = *reinterpret_cast<const v8s*>(&As[(wm*64 + mt*16 + mi)*32 + quad*8]);
    #pragma unroll
    for (int nt = 0; nt < 4; ++nt)
      bf[nt] = *reinterpret_cast<const v8s*>(&Bs[(wn*64 + nt*16 + mi)*32 + quad*8]);
    #pragma unroll
    for (int mt = 0; mt < 4; ++mt)
      #pragma unroll
      for (int nt = 0; nt < 4; ++nt)
        acc[mt][nt] = __builtin_amdgcn_mfma_f32_16x16x32_bf16(af[mt], bf[nt], acc[mt][nt], 0, 0, 0);
    __syncthreads();
  }

  #pragma unroll
  for (int nt = 0; nt < 4; ++nt) {
    const int col = n0 + wn*64 + nt*16 + mi;
    const float bc = bias[col];
    #pragma unroll
    for (int mt = 0; mt < 4; ++mt) {
      #pragma unroll
      for (int r = 0; r < 4; ++r) {
        const int row = m0 + wm*64 + mt*16 + quad*4 + r;
        float val = acc[mt][nt][r] + bc;
        if (mlp) val = tanhf(val);
        Cmat[(size_t)row * NN + col] = f2bb(val);
      }
    }
  }
}

// ---------------------------------------------------------------------------
// mlp stage 2 via MFMA — all-bf16 inputs (unchanged, passing)
// ---------------------------------------------------------------------------
__global__ __launch_bounds__(256) void mlp2_mfma(const u16* __restrict__ H,
                                                 const u16* __restrict__ W2B,
                                                 const float* __restrict__ b2,
                                                 float* __restrict__ outp)
{
  __shared__ u16 As[128 * 40];
  __shared__ u16 Bs[128 * 40];
  const int t = threadIdx.x;
  const int m0 = blockIdx.x * 128;
  const int wave = t >> 6, lane = t & 63;
  const int wm = wave >> 1, wn = wave & 1;
  const int mi = lane & 15, quad = lane >> 4;
  const int srow = t >> 1, scol = (t & 1) * 16;

  v4f acc[4][4];
  #pragma unroll
  for (int a = 0; a < 4; ++a)
    #pragma unroll
    for (int b = 0; b < 4; ++b) acc[a][b] = (v4f){0.f, 0.f, 0.f, 0.f};

  for (int kt = 0; kt < 256; kt += 32) {
    const u16* ap = H + (size_t)(m0 + srow) * 256 + kt + scol;
    *reinterpret_cast<uint4*>(&As[srow*40 + scol])     = *reinterpret_cast<const uint4*>(ap);
    *reinterpret_cast<uint4*>(&As[srow*40 + scol + 8]) = *reinterpret_cast<const uint4*>(ap + 8);
    const u16* bp = W2B + (size_t)srow * 256 + kt + scol;
    *reinterpret_cast<uint4*>(&Bs[srow*40 + scol])     = *reinterpret_cast<const uint4*>(bp);
    *reinterpret_cast<uint4*>(&Bs[srow*40 + scol + 8]) = *reinterpret_cast<const uint4*>(bp + 8);
    __syncthreads();

    v8s af[4], bf[4];
    #pragma unroll
    for (int mt = 0; mt < 4; ++mt)
      af[mt] = *reinterpret_cast<const v8s*>(&As[(wm*64 + mt*16 + mi)*40 + quad*8]);
    #pragma unroll
    for (int nt = 0; nt < 4; ++nt)
      bf[nt] = *reinterpret_cast<const v8s*>(&Bs[(wn*64 + nt*16 + mi)*40 + quad*8]);
    #pragma unroll
    for (int mt = 0; mt < 4; ++mt)
      #pragma unroll
      for (int nt = 0; nt < 4; ++nt)
        acc[mt][nt] = __builtin_amdgcn_mfma_f32_16x16x32_bf16(af[mt], bf[nt], acc[mt][nt], 0, 0, 0);
    __syncthreads();
  }

  #pragma unroll
  for (int nt = 0; nt < 4; ++nt) {
    const int col = wn*64 + nt*16 + mi;   // 0..127
    const float bc = b2[col];
    #pragma unroll
    for (int mt = 0; mt < 4; ++mt) {
      #pragma unroll
      for (int r = 0; r < 4; ++r) {
        const int row = m0 + wm*64 + mt*16 + quad*4 + r;
        const int bi = row / 3, s = row - bi * 3;
        outp[(size_t)s * (Bn*128) + (size_t)bi * 128 + col] = acc[mt][nt][r] + bc;
      }
    }
  }
}

// ---------------------------------------------------------------------------
// qkv via MFMA — 3 segments LOOPED in one block (grid 588): the 36.9 KB
// A-tile (xt) is segment-invariant, staged ONCE; only the 9.2 KB Bs reloads
// per segment. Cuts xt global reads 3x -> 1x. Sync pattern: sync(a) ensures
// prior segment's Bs reads done before overwrite; sync(b) makes Bs visible.
// A-fragments preloaded to registers (seg-invariant).
// ---------------------------------------------------------------------------
__global__ __launch_bounds__(256) void qkv_mfma(const u16* __restrict__ xt, const float* __restrict__ Wqkv,
                                                u16* __restrict__ qh, u16* __restrict__ kh, u16* __restrict__ vb)
{
  __shared__ u16 As[256 * 72];
  __shared__ u16 Bs[64 * 72];
  const int t = threadIdx.x;
  const int m0 = blockIdx.x * 256;
  const int wave = t >> 6, lane = t & 63;
  const int mi = lane & 15, quad = lane >> 4;

  {
    const int ar = t >> 2, ac = (t & 3) * 16;
    #pragma unroll
    for (int rb = 0; rb < 4; ++rb) {
      const int row = rb*64 + ar;
      const uint4* src = reinterpret_cast<const uint4*>(xt + ((size_t)(m0 + row))*64 + ac);
      *reinterpret_cast<uint4*>(&As[row*72 + ac])     = src[0];
      *reinterpret_cast<uint4*>(&As[row*72 + ac + 8]) = src[1];
    }
  }
  __syncthreads();   // As visible

  v8s af[2][4];      // seg-invariant A fragments
  #pragma unroll
  for (int ks = 0; ks < 2; ++ks)
    #pragma unroll
    for (int mt = 0; mt < 4; ++mt)
      af[ks][mt] = *reinterpret_cast<const v8s*>(&As[(wave*64 + mt*16 + mi)*72 + ks*32 + quad*8]);

  #pragma unroll 1
  for (int seg = 0; seg < 3; ++seg) {
    if (seg) __syncthreads();          // prior segment's Bs reads complete
    for (int i = t; i < Cc*Cc; i += 256) {
      const int j = i >> 6, c = i & 63;
      Bs[j*72 + c] = f2bb(Wqkv[(size_t)(seg*64 + j)*64 + c]);
    }
    __syncthreads();                   // Bs visible

    v4f acc[4][4];
    #pragma unroll
    for (int a = 0; a < 4; ++a)
      #pragma unroll
      for (int b = 0; b < 4; ++b) acc[a][b] = (v4f){0.f, 0.f, 0.f, 0.f};

    #pragma unroll
    for (int ks = 0; ks < 2; ++ks) {
      v8s bf[4];
      #pragma unroll
      for (int nt = 0; nt < 4; ++nt)
        bf[nt] = *reinterpret_cast<const v8s*>(&Bs[(nt*16 + mi)*72 + ks*32 + quad*8]);
      #pragma unroll
      for (int mt = 0; mt < 4; ++mt)
        #pragma unroll
        for (int nt = 0; nt < 4; ++nt)
          acc[mt][nt] = __builtin_amdgcn_mfma_f32_16x16x32_bf16(af[ks][mt], bf[nt], acc[mt][nt], 0, 0, 0);
    }

    u16* hm = (seg == 0) ? qh : kh;
    #pragma unroll
    for (int nt = 0; nt < 4; ++nt) {
      const int col = nt*16 + mi;
      const int h = col >> 3, d = col & 7;
      #pragma unroll
      for (int mt = 0; mt < 4; ++mt) {
        #pragma unroll
        for (int r = 0; r < 4; ++r) {
          const int row = m0 + wave*64 + mt*16 + quad*4 + r;
          const u16 val = f2bb(acc[mt][nt][r]);
          if (seg < 2) {
            const int b = row / Nc, n = row - b * Nc;
            hm[((size_t)(b*NHc + h)*Nc + n)*8 + d] = val;
          } else {
            vb[(size_t)row * 64 + col] = val;
          }
        }
      }
    }
  }
}

// ---------------------------------------------------------------------------
// fused agent attention v6 + exp2 (biases pre-scaled by log2e in conv_bias;
// structure byte-identical to the measured-best v6 otherwise)
// ---------------------------------------------------------------------------
__global__ __launch_bounds__(256) void attn_kernel(const u16* __restrict__ qh, const u16* __restrict__ kh,
                                                   const u16* __restrict__ v,
                                                   const float* __restrict__ pb, const float* __restrict__ ab,
                                                   u16* __restrict__ o)
{
  __shared__ float sU[Nc*10];        // union: sQ (Nc*8) then sPart (Nc*9 used)
  __shared__ float sK[Nc*8], sV[Nc*8];
  __shared__ float sAg[Ac*8], sAV[Ac*8];
  const int bh = blockIdx.x;
  const int b = bh >> 3, h = bh & 7;
  const int t = threadIdx.x;
  const float scale2 = 0.3535533905932738f * 1.4426950408889634f;  // scale * log2(e)

  float qreg[8];
  if (t < Nc) {
    const size_t base = ((size_t)bh * Nc + t) * 8;
    unpack8(*reinterpret_cast<const uint4*>(qh + base), qreg);
    #pragma unroll
    for (int d = 0; d < 8; ++d) sU[t*8 + d] = qreg[d];   // sQ view
    unpack8(*reinterpret_cast<const uint4*>(kh + base), &sK[t*8]);
    unpack8(*reinterpret_cast<const uint4*>(v + ((size_t)b*Nc + t)*64 + h*8), &sV[t*8]);
  }
  __syncthreads();

  for (int i = t; i < Ac*8; i += 256) {
    const int a = i >> 3, d = i & 7;
    const int ay = a / 7, ax = a % 7;
    const int n00 = (ay * 2) * WINc + ax * 2;
    sAg[i] = 0.25f * (sU[n00*8+d] + sU[(n00+1)*8+d] + sU[(n00+WINc)*8+d] + sU[(n00+WINc+1)*8+d]);
  }
  __syncthreads();   // sQ reads done; sU becomes sPart

  // stage 1: thread t<196 -> quarter qd, agent a; 2-way unrolled
  if (t < Nc) {
    const int qd = t / Ac, a = t - qd * Ac;
    const int nb = qd * Ac;
    v2f g2[4];
    #pragma unroll
    for (int d2 = 0; d2 < 4; ++d2) g2[d2] = *reinterpret_cast<const v2f*>(&sAg[a*8 + d2*2]);
    const float* pbr = pb + ((size_t)h*Nc + nb)*Ac + a;   // step Ac per j
    float l0 = 0.f, l1 = 0.f;
    v2f avA[4] = {}, avB[4] = {};
    for (int j = 0; j < 48; j += 2) {
      const v2f* k0 = reinterpret_cast<const v2f*>(&sK[(nb + j)*8]);
      const v2f* k1 = reinterpret_cast<const v2f*>(&sK[(nb + j + 1)*8]);
      v2f sa = (g2[0]*k0[0] + g2[1]*k0[1]) + (g2[2]*k0[2] + g2[3]*k0[3]);
      v2f sb = (g2[0]*k1[0] + g2[1]*k1[1]) + (g2[2]*k1[2] + g2[3]*k1[3]);
      const float e0 = exp2f(fmaf(sa.x + sa.y, scale2, pbr[j*Ac]));
      const float e1 = exp2f(fmaf(sb.x + sb.y, scale2, pbr[(j+1)*Ac]));
      l0 += e0; l1 += e1;
      const v2f* v0 = reinterpret_cast<const v2f*>(&sV[(nb + j)*8]);
      const v2f* v1 = reinterpret_cast<const v2f*>(&sV[(nb + j + 1)*8]);
      const v2f e02 = {e0, e0}, e12 = {e1, e1};
      #pragma unroll
      for (int d2 = 0; d2 < 4; ++d2) { avA[d2] += e02 * v0[d2]; avB[d2] += e12 * v1[d2]; }
    }
    { // tail j = 48
      const v2f* k0 = reinterpret_cast<const v2f*>(&sK[(nb + 48)*8]);
      v2f sa = (g2[0]*k0[0] + g2[1]*k0[1]) + (g2[2]*k0[2] + g2[3]*k0[3]);
      const float e0 = exp2f(fmaf(sa.x + sa.y, scale2, pbr[48*Ac]));
      l0 += e0;
      const v2f* v0 = reinterpret_cast<const v2f*>(&sV[(nb + 48)*8]);
      const v2f e02 = {e0, e0};
      #pragma unroll
      for (int d2 = 0; d2 < 4; ++d2) avA[d2] += e02 * v0[d2];
    }
    float* pp = &sU[t*9];            // sPart view
    pp[0] = l0 + l1;
    #pragma unroll
    for (int d2 = 0; d2 < 4; ++d2) {
      const v2f m = avA[d2] + avB[d2];
      pp[1+d2*2] = m.x; pp[2+d2*2] = m.y;
    }
  }
  __syncthreads();

  if (t < Ac) {
    float L = 0.f, av[8] = {};
    #pragma unroll
    for (int p = 0; p < 4; ++p) {
      const float* pp = &sU[(p*Ac + t)*9];
      L += pp[0];
      #pragma unroll
      for (int d = 0; d < 8; ++d) av[d] += pp[1+d];
    }
    const float inv = 1.f / L;
    #pragma unroll
    for (int d = 0; d < 8; ++d) sAV[t*8 + d] = av[d] * inv;
  }
  __syncthreads();

  // stage 2: thread = token n; 2-way unrolled over agents
  if (t < Nc) {
    v2f q2[4];
    #pragma unroll
    for (int d2 = 0; d2 < 4; ++d2) q2[d2] = (v2f){qreg[d2*2], qreg[d2*2+1]};
    const float* abr = ab + (size_t)h*Ac*Nc + t;          // step Nc per a
    float l0 = 0.f, l1 = 0.f;
    v2f oA[4] = {}, oB[4] = {};
    for (int a = 0; a < 48; a += 2) {
      const v2f* g0 = reinterpret_cast<const v2f*>(&sAg[a*8]);
      const v2f* g1 = reinterpret_cast<const v2f*>(&sAg[(a+1)*8]);
      v2f sa = (q2[0]*g0[0] + q2[1]*g0[1]) + (q2[2]*g0[2] + q2[3]*g0[3]);
      v2f sb = (q2[0]*g1[0] + q2[1]*g1[1]) + (q2[2]*g1[2] + q2[3]*g1[3]);
      const float e0 = exp2f(fmaf(sa.x + sa.y, scale2, abr[a*Nc]));
      const float e1 = exp2f(fmaf(sb.x + sb.y, scale2, abr[(a+1)*Nc]));
      l0 += e0; l1 += e1;
      const v2f* a0 = reinterpret_cast<const v2f*>(&sAV[a*8]);
      const v2f* a1 = reinterpret_cast<const v2f*>(&sAV[(a+1)*8]);
      const v2f e02 = {e0, e0}, e12 = {e1, e1};
      #pragma unroll
      for (int d2 = 0; d2 < 4; ++d2) { oA[d2] += e02 * a0[d2]; oB[d2] += e12 * a1[d2]; }
    }
    { // tail a = 48
      const v2f* g0 = reinterpret_cast<const v2f*>(&sAg[48*8]);
      v2f sa = (q2[0]*g0[0] + q2[1]*g0[1]) + (q2[2]*g0[2] + q2[3]*g0[3]);
      const float e0 = exp2f(fmaf(sa.x + sa.y, scale2, abr[48*Nc]));
      l0 += e0;
      const v2f* a0 = reinterpret_cast<const v2f*>(&sAV[48*8]);
      const v2f e02 = {e0, e0};
      #pragma unroll
      for (int d2 = 0; d2 < 4; ++d2) oA[d2] += e02 * a0[d2];
    }
    const float inv = 1.f / (l0 + l1);
    float o8[8];
    #pragma unroll
    for (int d2 = 0; d2 < 4; ++d2) {
      const v2f m = oA[d2] + oB[d2];
      o8[d2*2] = m.x * inv; o8[d2*2+1] = m.y * inv;
    }
    *reinterpret_cast<uint4*>(&o[((size_t)b*Nc + t)*64 + h*8]) = pack8(o8);
  }
}

// ---------------------------------------------------------------------------
// dwc 3x3 depthwise + residual, VECTORIZED (R9 version, measured good)
// ---------------------------------------------------------------------------
__global__ __launch_bounds__(256) void dwc_kernel(const u16* __restrict__ o, const u16* __restrict__ v,
                                                  const float* __restrict__ dwc_w, const float* __restrict__ dwc_b,
                                                  u16* __restrict__ U)
{
  __shared__ u16 sV[Nc*Cc];        // 25088 B
  __shared__ float sWw[9*64];      //  2304 B: wT[k][c] = dwc_w[c*9+k]
  const int b = blockIdx.x, t = threadIdx.x;

  const uint2* vsrc = reinterpret_cast<const uint2*>(v + (size_t)b * CNc);
  uint2* sV2 = reinterpret_cast<uint2*>(sV);
  for (int i = t; i < CNc/4; i += 256) sV2[i] = vsrc[i];
  for (int i = t; i < 9*64; i += 256) {
    const int k = i >> 6, c = i & 63;
    sWw[i] = dwc_w[c*9 + k];
  }
  __syncthreads();

  const int c0 = (t & 7) * 8;      // fixed channel block per thread
  float wreg[9][8], breg[8];
  #pragma unroll
  for (int k = 0; k < 9; ++k) {
    *reinterpret_cast<float4*>(&wreg[k][0]) = *reinterpret_cast<const float4*>(&sWw[k*64 + c0]);
    *reinterpret_cast<float4*>(&wreg[k][4]) = *reinterpret_cast<const float4*>(&sWw[k*64 + c0 + 4]);
  }
  *reinterpret_cast<float4*>(&breg[0]) = *reinterpret_cast<const float4*>(dwc_b + c0);
  *reinterpret_cast<float4*>(&breg[4]) = *reinterpret_cast<const float4*>(dwc_b + c0 + 4);

  const u16* ob = o + (size_t)b * CNc;
  u16* ub = U + (size_t)b * CNc;
  for (int i = t; i < CNc/8; i += 256) {     // 1568 items of 8 channels
    const int n = i >> 3;
    const int y = n / WINc, x = n % WINc;
    float acc[8], vv[8];
    unpack8(*reinterpret_cast<const uint4*>(ob + (size_t)i*8), acc);   // residual
    #pragma unroll
    for (int j = 0; j < 8; ++j) acc[j] += breg[j];                     // + bias
    #pragma unroll
    for (int ky = 0; ky < 3; ++ky) {
      const int yy = y + ky - 1;
      if (yy < 0 || yy >= WINc) continue;
      #pragma unroll
      for (int kx = 0; kx < 3; ++kx) {
        const int xx = x + kx - 1;
        if (xx < 0 || xx >= WINc) continue;
        const int k = ky*3 + kx;
        unpack8(*reinterpret_cast<const uint4*>(&sV[(yy*WINc + xx)*Cc + c0]), vv);
        #pragma unroll
        for (int j = 0; j < 8; ++j) acc[j] = fmaf(wreg[k][j], vv[j], acc[j]);
      }
    }
    *reinterpret_cast<uint4*>(ub + (size_t)i*8) = pack8(acc);
  }
}

// ---------------------------------------------------------------------------
// proj GEMM via MFMA (unchanged, passing)
// ---------------------------------------------------------------------------
__global__ __launch_bounds__(256) void proj_mfma(const u16* __restrict__ U,
                                                 const float* __restrict__ Wp,
                                                 const float* __restrict__ bp,
                                                 u16* __restrict__ oproj)
{
  __shared__ u16 As[256 * 72];
  __shared__ u16 Bs[64 * 72];
  const int t = threadIdx.x;
  const int m0 = blockIdx.x * 256;
  const int wave = t >> 6, lane = t & 63;
  const int mi = lane & 15, quad = lane >> 4;

  for (int i = t; i < Cc*Cc; i += 256) {
    const int j = i >> 6, c = i & 63;
    Bs[j*72 + c] = f2bb(Wp[i]);
  }
  {
    const int ar = t >> 2, ac = (t & 3) * 16;
    #pragma unroll
    for (int rb = 0; rb < 4; ++rb) {
      const int row = rb*64 + ar;
      const uint4* src = reinterpret_cast<const uint4*>(U + ((size_t)(m0 + row))*64 + ac);
      *reinterpret_cast<uint4*>(&As[row*72 + ac])     = src[0];
      *reinterpret_cast<uint4*>(&As[row*72 + ac + 8]) = src[1];
    }
  }
  __syncthreads();

  v4f acc[4][4];
  #pragma unroll
  for (int a = 0; a < 4; ++a)
    #pragma unroll
    for (int b = 0; b < 4; ++b) acc[a][b] = (v4f){0.f, 0.f, 0.f, 0.f};

  #pragma unroll
  for (int ks = 0; ks < 2; ++ks) {
    v8s af[4], bf[4];
    #pragma unroll
    for (int mt = 0; mt < 4; ++mt)
      af[mt] = *reinterpret_cast<const v8s*>(&As[(wave*64 + mt*16 + mi)*72 + ks*32 + quad*8]);
    #pragma unroll
    for (int nt = 0; nt < 4; ++nt)
      bf[nt] = *reinterpret_cast<const v8s*>(&Bs[(nt*16 + mi)*72 + ks*32 + quad*8]);
    #pragma unroll
    for (int mt = 0; mt < 4; ++mt)
      #pragma unroll
      for (int nt = 0; nt < 4; ++nt)
        acc[mt][nt] = __builtin_amdgcn_mfma_f32_16x16x32_bf16(af[mt], bf[nt], acc[mt][nt], 0, 0, 0);
  }

  #pragma unroll
  for (int nt = 0; nt < 4; ++nt) {
    const int col = nt*16 + mi;
    const float bc = bp[col];
    #pragma unroll
    for (int mt = 0; mt < 4; ++mt) {
      #pragma unroll
      for (int r = 0; r < 4; ++r) {
        const int row = m0 + wave*64 + mt*16 + quad*4 + r;
        oproj[(size_t)row * 64 + col] = f2bb(acc[mt][nt][r] + bc);
      }
    }
  }
}

// ---------------------------------------------------------------------------
// adjacency GEMM via MFMA, split-K(8), 128x128 tiles + global_load_lds
// (unchanged, passing)
// ---------------------------------------------------------------------------
__global__ __launch_bounds__(256) void gemm_adj_mfma(const u16* __restrict__ Amat,
                                                     const u16* __restrict__ BmatB,
                                                     float* __restrict__ part)
{
  constexpr int K = CNc, Kc = CNc/8;   // 1568 = 49*32
  __shared__ u16 As[128 * 32];
  __shared__ u16 Bs[128 * 32];
  const int t = threadIdx.x;
  const int n0 = blockIdx.x * 128, m0 = blockIdx.y * 128;
  const int kbeg = blockIdx.z * Kc;
  const int wave = t >> 6, lane = t & 63;
  const int wm = wave >> 1, wn = wave & 1;
  const int mi = lane & 15, quad = lane >> 4;

  v4f acc[4][4];
  #pragma unroll
  for (int a = 0; a < 4; ++a)
    #pragma unroll
    for (int b = 0; b < 4; ++b) acc[a][b] = (v4f){0.f, 0.f, 0.f, 0.f};

  const int rs = wave*32 + (lane >> 2);
  const int cs = (lane & 3) * 8;
  const u16* ga0 = Amat + (size_t)(m0 + rs) * K + kbeg + cs;
  const u16* ga1 = Amat + (size_t)(m0 + rs + 16) * K + kbeg + cs;
  const u16* gb0 = BmatB + (size_t)(n0 + rs) * K + kbeg + cs;
  const u16* gb1 = BmatB + (size_t)(n0 + rs + 16) * K + kbeg + cs;
  u16* la0 = &As[(wave*32)      * 32];
  u16* la1 = &As[(wave*32 + 16) * 32];
  u16* lb0 = &Bs[(wave*32)      * 32];
  u16* lb1 = &Bs[(wave*32 + 16) * 32];

  for (int kt = 0; kt < Kc; kt += 32) {
    gl_lds16(ga0 + kt, la0);
    gl_lds16(ga1 + kt, la1);
    gl_lds16(gb0 + kt, lb0);
    gl_lds16(gb1 + kt, lb1);
    __syncthreads();

    v8s af[4], bf[4];
    #pragma unroll
    for (int mt = 0; mt < 4; ++mt)
      af[mt] = *reinterpret_cast<const v8s*>(&As[(wm*64 + mt*16 + mi)*32 + quad*8]);
    #pragma unroll
    for (int nt = 0; nt < 4; ++nt)
      bf[nt] = *reinterpret_cast<const v8s*>(&Bs[(wn*64 + nt*16 + mi)*32 + quad*8]);
    #pragma unroll
    for (int mt = 0; mt < 4; ++mt)
      #pragma unroll
      for (int nt = 0; nt < 4; ++nt)
        acc[mt][nt] = __builtin_amdgcn_mfma_f32_16x16x32_bf16(af[mt], bf[nt], acc[mt][nt], 0, 0, 0);
    __syncthreads();
  }

  const size_t zoff = (size_t)blockIdx.z * B3c * 256;
  #pragma unroll
  for (int nt = 0; nt < 4; ++nt) {
    const int col = n0 + wn*64 + nt*16 + mi;
    #pragma unroll
    for (int mt = 0; mt < 4; ++mt) {
      #pragma unroll
      for (int r = 0; r < 4; ++r) {
        const int row = m0 + wm*64 + mt*16 + quad*4 + r;
        part[zoff + (size_t)row * 256 + col] = acc[mt][nt][r];
      }
    }
  }
}

__global__ __launch_bounds__(256) void reduce_bias_kernel(const float* __restrict__ part,
                                                          const float* __restrict__ bias,
                                                          float* __restrict__ outp)
{
  const int idx = blockIdx.x * 256 + threadIdx.x;   // 768*256 exact
  const int n = idx & 255;
  float acc = bias[n];
  #pragma unroll
  for (int s = 0; s < 8; ++s) acc += part[(size_t)s * B3c * 256 + idx];
  outp[idx] = acc;                                  // fp32 output
}

// ---------------------------------------------------------------------------
extern "C" void kernel_launch(void* const* d_in, const int* in_sizes, int n_in,
                              void* d_out, int out_size, void* d_ws, size_t ws_size,
                              hipStream_t stream)
{
  auto in = [&](int i){ return reinterpret_cast<const float*>(d_in[i]); };
  const float *X = in(0), *We = in(1), *be = in(2), *Wq = in(3), *Wp = in(4), *bp = in(5),
              *dww = in(6), *dwb = in(7), *anb = in(8), *nab = in(9), *ahb = in(10), *awb = in(11),
              *hab = in(12), *wab = in(13), *Wadj = in(14), *badj = in(15),
              *W1 = in(16), *b1 = in(17), *W2 = in(18), *b2 = in(19);
  float* out = reinterpret_cast<float*>(d_out);
  char* w = reinterpret_cast<char*>(d_ws);

  const size_t TOK = (size_t)B3c * CNc;          // 9,633,792 elements
  u16* xt = reinterpret_cast<u16*>(w);            // slot0: xt -> o -> oproj
  u16* qh = reinterpret_cast<u16*>(w + TOK*2);    // slot1: We_bf[0:] -> q head-major -> U
  u16* kh = reinterpret_cast<u16*>(w + TOK*4);    // slot2: We_bf[..] -> k head-major -> part
  u16* vb = reinterpret_cast<u16*>(w + TOK*6);    // slot3: v token-major
  float* pb = reinterpret_cast<float*>(w + TOK*8);
  float* ab = pb + NHc*Ac*Nc;
  u16* WadjB = reinterpret_cast<u16*>(ab + NHc*Ac*Nc);   // 6.4 MB, persistent
  u16* XB  = WadjB + WadjN;                       // 2.0 MB, persistent (spare region)
  u16* W1B = XB + XN;                             // 0.66 MB, persistent
  u16* W2B = W1B + W1N;                           // 64 KB, persistent
  u16* H   = W2B + W2N;                           // 0.39 MB, persistent (written early, read last)
  u16* WeB = qh;                                  // 32.1 MB spans slot1+slot2 (38.5 MB)
  u16* U = qh;                                    // alias: qh dead after attn
  float* part = reinterpret_cast<float*>(kh);     // alias: kh dead after attn
  // total ws use: ~87.2 MB (<= 93.6 MB proven in R3)

  conv_bias_kernel<<<dim3(CONVB + BIASB), 256, 0, stream>>>(
      We, X, Wadj, W1, W2, WeB, XB, WadjB, W1B, W2B,
      anb, nab, ahb, awb, hab, wab, pb, ab);
  gemm_embed_mlp1<<<dim3(100, B3c/128), 256, 0, stream>>>(XB, WeB, W1B, be, b1, xt, H);
  qkv_mfma<<<dim3((B3c*Nc)/256), 256, 0, stream>>>(xt, Wq, qh, kh, vb);
  attn_kernel<<<dim3(B3c*NHc), 256, 0, stream>>>(qh, kh, vb, pb, ab, xt /*o*/);
  dwc_kernel<<<dim3(B3c), 256, 0, stream>>>(xt /*o*/, vb, dww, dwb, U);
  proj_mfma<<<dim3((B3c*Nc)/256), 256, 0, stream>>>(U, Wp, bp, xt /*oproj*/);
  gemm_adj_mfma<<<dim3(256/128, B3c/128, 8), 256, 0, stream>>>(xt /*oproj*/, WadjB, part);
  reduce_bias_kernel<<<dim3((B3c*256)/256), 256, 0, stream>>>(part, badj, out + 3*Bn*128);
  mlp2_mfma<<<dim3(B3c/128), 256, 0, stream>>>(H, W2B, b2, out);
}

// Round 13
// 416.481 us; speedup vs baseline: 1.0341x; 1.0341x over previous
//
#include <hip/hip_runtime.h>

using u16 = unsigned short;
using u32 = unsigned int;

constexpr int Bn   = 256;
constexpr int Dd   = 1280;
constexpr int Cc   = 64;
constexpr int WINc = 14;
constexpr int NHc  = 8;
constexpr int Ac   = 49;
constexpr int Nc   = WINc * WINc;   // 196
constexpr int HDc  = Cc / NHc;      // 8
constexpr int B3c  = 3 * Bn;        // 768
constexpr int CNc  = Cc * Nc;       // 12544

typedef __attribute__((ext_vector_type(8))) short v8s;   // 8 bf16 = 4 VGPRs
typedef __attribute__((ext_vector_type(4))) float v4f;
typedef __attribute__((ext_vector_type(2))) float v2f;   // packed fp32 (v_pk_*)

// bf16 helpers: inputs fp32, workspace intermediates bf16, OUTPUT fp32.
__device__ __forceinline__ float bflo(u32 u){ union{u32 x; float f;} c; c.x = u << 16; return c.f; }
__device__ __forceinline__ float bfhi(u32 u){ union{u32 x; float f;} c; c.x = u & 0xffff0000u; return c.f; }
__device__ __forceinline__ float bfs(u16 h){ union{u32 x; float f;} c; c.x = ((u32)h) << 16; return c.f; }
__device__ __forceinline__ u16 f2bb(float f){
  u32 u = __float_as_uint(f);
  u32 r = (u + 0x7fffu + ((u >> 16) & 1u)) >> 16;
  return (u16)r;
}
__device__ __forceinline__ void unpack8(uint4 u, float* dst){
  dst[0]=bflo(u.x); dst[1]=bfhi(u.x); dst[2]=bflo(u.y); dst[3]=bfhi(u.y);
  dst[4]=bflo(u.z); dst[5]=bfhi(u.z); dst[6]=bflo(u.w); dst[7]=bfhi(u.w);
}
__device__ __forceinline__ uint4 pack8(const float* s){
  uint4 r;
  r.x = (u32)f2bb(s[0]) | ((u32)f2bb(s[1]) << 16);
  r.y = (u32)f2bb(s[2]) | ((u32)f2bb(s[3]) << 16);
  r.z = (u32)f2bb(s[4]) | ((u32)f2bb(s[5]) << 16);
  r.w = (u32)f2bb(s[6]) | ((u32)f2bb(s[7]) << 16);
  return r;
}

// raw hardware exp2: single v_exp_f32, no libm denormal guard (args bounded here)
__device__ __forceinline__ float hexp2(float x){ return __builtin_amdgcn_exp2f(x); }

// async global->LDS, 16B per lane; LDS dest = wave-uniform base + lane*16
__device__ __forceinline__ void gl_lds16(const u16* g, u16* l){
  __builtin_amdgcn_global_load_lds(
      (const __attribute__((address_space(1))) unsigned int*)g,
      (__attribute__((address_space(3))) unsigned int*)l,
      16, 0, 0);
}

// ---------------------------------------------------------------------------
// One-time fp32->bf16 conversion of W_embed, X, W_adj, W1, W2,
// PLUS (fused) position-bias precompute. Biases pre-scaled by log2(e) so
// attn uses hw exp2 (one fma + v_exp per score).
// ---------------------------------------------------------------------------
constexpr int WeN   = 12544 * 1280;   // 16,056,320
constexpr int XN    = 768 * 1280;     //    983,040
constexpr int WadjN = 256 * CNc;      //  3,211,264
constexpr int W1N   = 256 * 1280;     //    327,680
constexpr int W2N   = 128 * 256;      //     32,768
constexpr int CONVB = (WeN + XN + WadjN + W1N + W2N) / (256*8);   // 10064
constexpr int BIASB = (2 * NHc * Ac * Nc + 255) / 256;            // 601
__global__ __launch_bounds__(256) void conv_bias_kernel(const float* __restrict__ We,
                                                        const float* __restrict__ X,
                                                        const float* __restrict__ Wadj,
                                                        const float* __restrict__ W1,
                                                        const float* __restrict__ W2,
                                                        u16* __restrict__ WeB,
                                                        u16* __restrict__ XB,
                                                        u16* __restrict__ WadjB,
                                                        u16* __restrict__ W1B,
                                                        u16* __restrict__ W2B,
                                                        const float* __restrict__ an, const float* __restrict__ na,
                                                        const float* __restrict__ ah, const float* __restrict__ aw,
                                                        const float* __restrict__ ha, const float* __restrict__ wa,
                                                        float* __restrict__ pb, float* __restrict__ ab)
{
  if (blockIdx.x >= CONVB) {
    // ---- bias path (math identical; output scaled by LOG2E) ----
    constexpr float LOG2E = 1.4426950408889634f;
    const int total = NHc * Ac * Nc;   // 76832
    int idx = (blockIdx.x - CONVB) * 256 + threadIdx.x;
    if (idx >= 2 * total) return;
    const bool isab = idx >= total;
    const int r = isab ? idx - total : idx;
    const int h = r / (Ac * Nc);
    const int r2 = r % (Ac * Nc);
    int a, n;
    if (isab) { n = r2 / Ac; a = r2 % Ac; } else { a = r2 / Nc; n = r2 % Nc; }
    const int y = n / WINc, x = n % WINc;
    float sy = fminf(fmaxf(0.5f * y - 0.25f, 0.f), 6.f);
    float sx = fminf(fmaxf(0.5f * x - 0.25f, 0.f), 6.f);
    const int y0 = (int)sy, x0 = (int)sx;
    const float wy = sy - y0, wx = sx - x0;
    const int y1 = (y0 + 1 < 6) ? y0 + 1 : 6;
    const int x1 = (x0 + 1 < 6) ? x0 + 1 : 6;
    const float* src = (isab ? na : an) + (h * Ac + a) * 49;
    const float v00 = src[y0*7 + x0], v01 = src[y0*7 + x1];
    const float v10 = src[y1*7 + x0], v11 = src[y1*7 + x1];
    const float bi = (1.f - wy) * ((1.f - wx) * v00 + wx * v01)
                   + wy * ((1.f - wx) * v10 + wx * v11);
    if (!isab) pb[((size_t)h*Nc + n)*Ac + a] = (bi + ah[(h*Ac + a)*WINc + y] + aw[(h*Ac + a)*WINc + x]) * LOG2E;
    else       ab[((size_t)h*Ac + a)*Nc + n] = (bi + ha[(h*WINc + y)*Ac + a] + wa[(h*WINc + x)*Ac + a]) * LOG2E;
    return;
  }
  // ---- conv path ----
  const size_t idx = ((size_t)blockIdx.x * 256 + threadIdx.x) * 8;
  const float* src; u16* dst;
  if (idx < (size_t)WeN)                          { src = We + idx;                         dst = WeB + idx; }
  else if (idx < (size_t)WeN + XN)                { src = X + (idx - WeN);                  dst = XB + (idx - WeN); }
  else if (idx < (size_t)WeN + XN + WadjN)        { src = Wadj + (idx - WeN - XN);          dst = WadjB + (idx - WeN - XN); }
  else if (idx < (size_t)WeN + XN + WadjN + W1N)  { src = W1 + (idx - WeN - XN - WadjN);    dst = W1B + (idx - WeN - XN - WadjN); }
  else                                            { src = W2 + (idx - WeN - XN - WadjN - W1N); dst = W2B + (idx - WeN - XN - WadjN - W1N); }
  float v[8];
  *reinterpret_cast<float4*>(&v[0]) = *reinterpret_cast<const float4*>(src);
  *reinterpret_cast<float4*>(&v[4]) = *reinterpret_cast<const float4*>(src + 4);
  *reinterpret_cast<uint4*>(dst) = pack8(v);
}

// ---------------------------------------------------------------------------
// MERGED embed + mlp1 GEMM (same K=1280, same A=XB): blocks x<98 compute
// embed (B=WeB, N=12544, no tanh); x>=98 compute mlp1 (B=W1B, N=256, tanh).
// m97-style global_load_lds staging, 128x128 tile, 2-barrier K loop.
// ---------------------------------------------------------------------------
__global__ __launch_bounds__(256) void gemm_embed_mlp1(const u16* __restrict__ XB,
                                                       const u16* __restrict__ WeB,
                                                       const u16* __restrict__ W1B,
                                                       const float* __restrict__ be,
                                                       const float* __restrict__ b1,
                                                       u16* __restrict__ xt,
                                                       u16* __restrict__ H)
{
  constexpr int KK = Dd;
  __shared__ u16 As[128 * 32];
  __shared__ u16 Bs[128 * 32];
  const int t = threadIdx.x;
  const bool mlp = blockIdx.x >= 98;
  const int n0 = (mlp ? (blockIdx.x - 98) : blockIdx.x) * 128;
  const int m0 = blockIdx.y * 128;
  const u16* Bmat = mlp ? W1B : WeB;
  const float* bias = mlp ? b1 : be;
  u16* Cmat = mlp ? H : xt;
  const int NN = mlp ? 256 : CNc;
  const int wave = t >> 6, lane = t & 63;
  const int wm = wave >> 1, wn = wave & 1;
  const int mi = lane & 15, quad = lane >> 4;

  v4f acc[4][4];
  #pragma unroll
  for (int a = 0; a < 4; ++a)
    #pragma unroll
    for (int b = 0; b < 4; ++b) acc[a][b] = (v4f){0.f, 0.f, 0.f, 0.f};

  const int rs = wave*32 + (lane >> 2);
  const int cs = (lane & 3) * 8;
  const u16* ga0 = XB + (size_t)(m0 + rs) * KK + cs;
  const u16* ga1 = XB + (size_t)(m0 + rs + 16) * KK + cs;
  const u16* gb0 = Bmat + (size_t)(n0 + rs) * KK + cs;
  const u16* gb1 = Bmat + (size_t)(n0 + rs + 16) * KK + cs;
  u16* la0 = &As[(wave*32)      * 32];
  u16* la1 = &As[(wave*32 + 16) * 32];
  u16* lb0 = &Bs[(wave*32)      * 32];
  u16* lb1 = &Bs[(wave*32 + 16) * 32];

  for (int kt = 0; kt < KK; kt += 32) {
    gl_lds16(ga0 + kt, la0);
    gl_lds16(ga1 + kt, la1);
    gl_lds16(gb0 + kt, lb0);
    gl_lds16(gb1 + kt, lb1);
    __syncthreads();

    v8s af[4], bf[4];
    #pragma unroll
    for (int mt = 0; mt < 4; ++mt)
      af[mt] = *reinterpret_cast<const v8s*>(&As[(wm*64 + mt*16 + mi)*32 + quad*8]);
    #pragma unroll
    for (int nt = 0; nt < 4; ++nt)
      bf[nt] = *reinterpret_cast<const v8s*>(&Bs[(wn*64 + nt*16 + mi)*32 + quad*8]);
    #pragma unroll
    for (int mt = 0; mt < 4; ++mt)
      #pragma unroll
      for (int nt = 0; nt < 4; ++nt)
        acc[mt][nt] = __builtin_amdgcn_mfma_f32_16x16x32_bf16(af[mt], bf[nt], acc[mt][nt], 0, 0, 0);
    __syncthreads();
  }

  #pragma unroll
  for (int nt = 0; nt < 4; ++nt) {
    const int col = n0 + wn*64 + nt*16 + mi;
    const float bc = bias[col];
    #pragma unroll
    for (int mt = 0; mt < 4; ++mt) {
      #pragma unroll
      for (int r = 0; r < 4; ++r) {
        const int row = m0 + wm*64 + mt*16 + quad*4 + r;
        float val = acc[mt][nt][r] + bc;
        if (mlp) val = tanhf(val);
        Cmat[(size_t)row * NN + col] = f2bb(val);
      }
    }
  }
}

// ---------------------------------------------------------------------------
// mlp stage 2 via MFMA — all-bf16 inputs (unchanged, passing)
// ---------------------------------------------------------------------------
__global__ __launch_bounds__(256) void mlp2_mfma(const u16* __restrict__ H,
                                                 const u16* __restrict__ W2B,
                                                 const float* __restrict__ b2,
                                                 float* __restrict__ outp)
{
  __shared__ u16 As[128 * 40];
  __shared__ u16 Bs[128 * 40];
  const int t = threadIdx.x;
  const int m0 = blockIdx.x * 128;
  const int wave = t >> 6, lane = t & 63;
  const int wm = wave >> 1, wn = wave & 1;
  const int mi = lane & 15, quad = lane >> 4;
  const int srow = t >> 1, scol = (t & 1) * 16;

  v4f acc[4][4];
  #pragma unroll
  for (int a = 0; a < 4; ++a)
    #pragma unroll
    for (int b = 0; b < 4; ++b) acc[a][b] = (v4f){0.f, 0.f, 0.f, 0.f};

  for (int kt = 0; kt < 256; kt += 32) {
    const u16* ap = H + (size_t)(m0 + srow) * 256 + kt + scol;
    *reinterpret_cast<uint4*>(&As[srow*40 + scol])     = *reinterpret_cast<const uint4*>(ap);
    *reinterpret_cast<uint4*>(&As[srow*40 + scol + 8]) = *reinterpret_cast<const uint4*>(ap + 8);
    const u16* bp = W2B + (size_t)srow * 256 + kt + scol;
    *reinterpret_cast<uint4*>(&Bs[srow*40 + scol])     = *reinterpret_cast<const uint4*>(bp);
    *reinterpret_cast<uint4*>(&Bs[srow*40 + scol + 8]) = *reinterpret_cast<const uint4*>(bp + 8);
    __syncthreads();

    v8s af[4], bf[4];
    #pragma unroll
    for (int mt = 0; mt < 4; ++mt)
      af[mt] = *reinterpret_cast<const v8s*>(&As[(wm*64 + mt*16 + mi)*40 + quad*8]);
    #pragma unroll
    for (int nt = 0; nt < 4; ++nt)
      bf[nt] = *reinterpret_cast<const v8s*>(&Bs[(wn*64 + nt*16 + mi)*40 + quad*8]);
    #pragma unroll
    for (int mt = 0; mt < 4; ++mt)
      #pragma unroll
      for (int nt = 0; nt < 4; ++nt)
        acc[mt][nt] = __builtin_amdgcn_mfma_f32_16x16x32_bf16(af[mt], bf[nt], acc[mt][nt], 0, 0, 0);
    __syncthreads();
  }

  #pragma unroll
  for (int nt = 0; nt < 4; ++nt) {
    const int col = wn*64 + nt*16 + mi;   // 0..127
    const float bc = b2[col];
    #pragma unroll
    for (int mt = 0; mt < 4; ++mt) {
      #pragma unroll
      for (int r = 0; r < 4; ++r) {
        const int row = m0 + wm*64 + mt*16 + quad*4 + r;
        const int bi = row / 3, s = row - bi * 3;
        outp[(size_t)s * (Bn*128) + (size_t)bi * 128 + col] = acc[mt][nt][r] + bc;
      }
    }
  }
}

// ---------------------------------------------------------------------------
// qkv via MFMA — 3 segments LOOPED in one block (grid 588, R12 version)
// ---------------------------------------------------------------------------
__global__ __launch_bounds__(256) void qkv_mfma(const u16* __restrict__ xt, const float* __restrict__ Wqkv,
                                                u16* __restrict__ qh, u16* __restrict__ kh, u16* __restrict__ vb)
{
  __shared__ u16 As[256 * 72];
  __shared__ u16 Bs[64 * 72];
  const int t = threadIdx.x;
  const int m0 = blockIdx.x * 256;
  const int wave = t >> 6, lane = t & 63;
  const int mi = lane & 15, quad = lane >> 4;

  {
    const int ar = t >> 2, ac = (t & 3) * 16;
    #pragma unroll
    for (int rb = 0; rb < 4; ++rb) {
      const int row = rb*64 + ar;
      const uint4* src = reinterpret_cast<const uint4*>(xt + ((size_t)(m0 + row))*64 + ac);
      *reinterpret_cast<uint4*>(&As[row*72 + ac])     = src[0];
      *reinterpret_cast<uint4*>(&As[row*72 + ac + 8]) = src[1];
    }
  }
  __syncthreads();   // As visible

  v8s af[2][4];      // seg-invariant A fragments
  #pragma unroll
  for (int ks = 0; ks < 2; ++ks)
    #pragma unroll
    for (int mt = 0; mt < 4; ++mt)
      af[ks][mt] = *reinterpret_cast<const v8s*>(&As[(wave*64 + mt*16 + mi)*72 + ks*32 + quad*8]);

  #pragma unroll 1
  for (int seg = 0; seg < 3; ++seg) {
    if (seg) __syncthreads();          // prior segment's Bs reads complete
    for (int i = t; i < Cc*Cc; i += 256) {
      const int j = i >> 6, c = i & 63;
      Bs[j*72 + c] = f2bb(Wqkv[(size_t)(seg*64 + j)*64 + c]);
    }
    __syncthreads();                   // Bs visible

    v4f acc[4][4];
    #pragma unroll
    for (int a = 0; a < 4; ++a)
      #pragma unroll
      for (int b = 0; b < 4; ++b) acc[a][b] = (v4f){0.f, 0.f, 0.f, 0.f};

    #pragma unroll
    for (int ks = 0; ks < 2; ++ks) {
      v8s bf[4];
      #pragma unroll
      for (int nt = 0; nt < 4; ++nt)
        bf[nt] = *reinterpret_cast<const v8s*>(&Bs[(nt*16 + mi)*72 + ks*32 + quad*8]);
      #pragma unroll
      for (int mt = 0; mt < 4; ++mt)
        #pragma unroll
        for (int nt = 0; nt < 4; ++nt)
          acc[mt][nt] = __builtin_amdgcn_mfma_f32_16x16x32_bf16(af[ks][mt], bf[nt], acc[mt][nt], 0, 0, 0);
    }

    u16* hm = (seg == 0) ? qh : kh;
    #pragma unroll
    for (int nt = 0; nt < 4; ++nt) {
      const int col = nt*16 + mi;
      const int h = col >> 3, d = col & 7;
      #pragma unroll
      for (int mt = 0; mt < 4; ++mt) {
        #pragma unroll
        for (int r = 0; r < 4; ++r) {
          const int row = m0 + wave*64 + mt*16 + quad*4 + r;
          const u16 val = f2bb(acc[mt][nt][r]);
          if (seg < 2) {
            const int b = row / Nc, n = row - b * Nc;
            hm[((size_t)(b*NHc + h)*Nc + n)*8 + d] = val;
          } else {
            vb[(size_t)row * 64 + col] = val;
          }
        }
      }
    }
  }
}

// ---------------------------------------------------------------------------
// fused agent attention v6 + hw-exp2: pre-scaled biases + hexp2 (raw
// v_exp_f32). R12's libm exp2f added guard VALU ops (VALUBusy 66->76%,
// +10 µs); hexp2 is the fast path the original __expf used, minus its mul.
// ---------------------------------------------------------------------------
__global__ __launch_bounds__(256) void attn_kernel(const u16* __restrict__ qh, const u16* __restrict__ kh,
                                                   const u16* __restrict__ v,
                                                   const float* __restrict__ pb, const float* __restrict__ ab,
                                                   u16* __restrict__ o)
{
  __shared__ float sU[Nc*10];        // union: sQ (Nc*8) then sPart (Nc*9 used)
  __shared__ float sK[Nc*8], sV[Nc*8];
  __shared__ float sAg[Ac*8], sAV[Ac*8];
  const int bh = blockIdx.x;
  const int b = bh >> 3, h = bh & 7;
  const int t = threadIdx.x;
  const float scale2 = 0.3535533905932738f * 1.4426950408889634f;  // scale * log2(e)

  float qreg[8];
  if (t < Nc) {
    const size_t base = ((size_t)bh * Nc + t) * 8;
    unpack8(*reinterpret_cast<const uint4*>(qh + base), qreg);
    #pragma unroll
    for (int d = 0; d < 8; ++d) sU[t*8 + d] = qreg[d];   // sQ view
    unpack8(*reinterpret_cast<const uint4*>(kh + base), &sK[t*8]);
    unpack8(*reinterpret_cast<const uint4*>(v + ((size_t)b*Nc + t)*64 + h*8), &sV[t*8]);
  }
  __syncthreads();

  for (int i = t; i < Ac*8; i += 256) {
    const int a = i >> 3, d = i & 7;
    const int ay = a / 7, ax = a % 7;
    const int n00 = (ay * 2) * WINc + ax * 2;
    sAg[i] = 0.25f * (sU[n00*8+d] + sU[(n00+1)*8+d] + sU[(n00+WINc)*8+d] + sU[(n00+WINc+1)*8+d]);
  }
  __syncthreads();   // sQ reads done; sU becomes sPart

  // stage 1: thread t<196 -> quarter qd, agent a; 2-way unrolled
  if (t < Nc) {
    const int qd = t / Ac, a = t - qd * Ac;
    const int nb = qd * Ac;
    v2f g2[4];
    #pragma unroll
    for (int d2 = 0; d2 < 4; ++d2) g2[d2] = *reinterpret_cast<const v2f*>(&sAg[a*8 + d2*2]);
    const float* pbr = pb + ((size_t)h*Nc + nb)*Ac + a;   // step Ac per j
    float l0 = 0.f, l1 = 0.f;
    v2f avA[4] = {}, avB[4] = {};
    for (int j = 0; j < 48; j += 2) {
      const v2f* k0 = reinterpret_cast<const v2f*>(&sK[(nb + j)*8]);
      const v2f* k1 = reinterpret_cast<const v2f*>(&sK[(nb + j + 1)*8]);
      v2f sa = (g2[0]*k0[0] + g2[1]*k0[1]) + (g2[2]*k0[2] + g2[3]*k0[3]);
      v2f sb = (g2[0]*k1[0] + g2[1]*k1[1]) + (g2[2]*k1[2] + g2[3]*k1[3]);
      const float e0 = hexp2(fmaf(sa.x + sa.y, scale2, pbr[j*Ac]));
      const float e1 = hexp2(fmaf(sb.x + sb.y, scale2, pbr[(j+1)*Ac]));
      l0 += e0; l1 += e1;
      const v2f* v0 = reinterpret_cast<const v2f*>(&sV[(nb + j)*8]);
      const v2f* v1 = reinterpret_cast<const v2f*>(&sV[(nb + j + 1)*8]);
      const v2f e02 = {e0, e0}, e12 = {e1, e1};
      #pragma unroll
      for (int d2 = 0; d2 < 4; ++d2) { avA[d2] += e02 * v0[d2]; avB[d2] += e12 * v1[d2]; }
    }
    { // tail j = 48
      const v2f* k0 = reinterpret_cast<const v2f*>(&sK[(nb + 48)*8]);
      v2f sa = (g2[0]*k0[0] + g2[1]*k0[1]) + (g2[2]*k0[2] + g2[3]*k0[3]);
      const float e0 = hexp2(fmaf(sa.x + sa.y, scale2, pbr[48*Ac]));
      l0 += e0;
      const v2f* v0 = reinterpret_cast<const v2f*>(&sV[(nb + 48)*8]);
      const v2f e02 = {e0, e0};
      #pragma unroll
      for (int d2 = 0; d2 < 4; ++d2) avA[d2] += e02 * v0[d2];
    }
    float* pp = &sU[t*9];            // sPart view
    pp[0] = l0 + l1;
    #pragma unroll
    for (int d2 = 0; d2 < 4; ++d2) {
      const v2f m = avA[d2] + avB[d2];
      pp[1+d2*2] = m.x; pp[2+d2*2] = m.y;
    }
  }
  __syncthreads();

  if (t < Ac) {
    float L = 0.f, av[8] = {};
    #pragma unroll
    for (int p = 0; p < 4; ++p) {
      const float* pp = &sU[(p*Ac + t)*9];
      L += pp[0];
      #pragma unroll
      for (int d = 0; d < 8; ++d) av[d] += pp[1+d];
    }
    const float inv = 1.f / L;
    #pragma unroll
    for (int d = 0; d < 8; ++d) sAV[t*8 + d] = av[d] * inv;
  }
  __syncthreads();

  // stage 2: thread = token n; 2-way unrolled over agents
  if (t < Nc) {
    v2f q2[4];
    #pragma unroll
    for (int d2 = 0; d2 < 4; ++d2) q2[d2] = (v2f){qreg[d2*2], qreg[d2*2+1]};
    const float* abr = ab + (size_t)h*Ac*Nc + t;          // step Nc per a
    float l0 = 0.f, l1 = 0.f;
    v2f oA[4] = {}, oB[4] = {};
    for (int a = 0; a < 48; a += 2) {
      const v2f* g0 = reinterpret_cast<const v2f*>(&sAg[a*8]);
      const v2f* g1 = reinterpret_cast<const v2f*>(&sAg[(a+1)*8]);
      v2f sa = (q2[0]*g0[0] + q2[1]*g0[1]) + (q2[2]*g0[2] + q2[3]*g0[3]);
      v2f sb = (q2[0]*g1[0] + q2[1]*g1[1]) + (q2[2]*g1[2] + q2[3]*g1[3]);
      const float e0 = hexp2(fmaf(sa.x + sa.y, scale2, abr[a*Nc]));
      const float e1 = hexp2(fmaf(sb.x + sb.y, scale2, abr[(a+1)*Nc]));
      l0 += e0; l1 += e1;
      const v2f* a0 = reinterpret_cast<const v2f*>(&sAV[a*8]);
      const v2f* a1 = reinterpret_cast<const v2f*>(&sAV[(a+1)*8]);
      const v2f e02 = {e0, e0}, e12 = {e1, e1};
      #pragma unroll
      for (int d2 = 0; d2 < 4; ++d2) { oA[d2] += e02 * a0[d2]; oB[d2] += e12 * a1[d2]; }
    }
    { // tail a = 48
      const v2f* g0 = reinterpret_cast<const v2f*>(&sAg[48*8]);
      v2f sa = (q2[0]*g0[0] + q2[1]*g0[1]) + (q2[2]*g0[2] + q2[3]*g0[3]);
      const float e0 = hexp2(fmaf(sa.x + sa.y, scale2, abr[48*Nc]));
      l0 += e0;
      const v2f* a0 = reinterpret_cast<const v2f*>(&sAV[48*8]);
      const v2f e02 = {e0, e0};
      #pragma unroll
      for (int d2 = 0; d2 < 4; ++d2) oA[d2] += e02 * a0[d2];
    }
    const float inv = 1.f / (l0 + l1);
    float o8[8];
    #pragma unroll
    for (int d2 = 0; d2 < 4; ++d2) {
      const v2f m = oA[d2] + oB[d2];
      o8[d2*2] = m.x * inv; o8[d2*2+1] = m.y * inv;
    }
    *reinterpret_cast<uint4*>(&o[((size_t)b*Nc + t)*64 + h*8]) = pack8(o8);
  }
}

// ---------------------------------------------------------------------------
// dwc 3x3 depthwise + residual, VECTORIZED (R9 version, measured good)
// ---------------------------------------------------------------------------
__global__ __launch_bounds__(256) void dwc_kernel(const u16* __restrict__ o, const u16* __restrict__ v,
                                                  const float* __restrict__ dwc_w, const float* __restrict__ dwc_b,
                                                  u16* __restrict__ U)
{
  __shared__ u16 sV[Nc*Cc];        // 25088 B
  __shared__ float sWw[9*64];      //  2304 B: wT[k][c] = dwc_w[c*9+k]
  const int b = blockIdx.x, t = threadIdx.x;

  const uint2* vsrc = reinterpret_cast<const uint2*>(v + (size_t)b * CNc);
  uint2* sV2 = reinterpret_cast<uint2*>(sV);
  for (int i = t; i < CNc/4; i += 256) sV2[i] = vsrc[i];
  for (int i = t; i < 9*64; i += 256) {
    const int k = i >> 6, c = i & 63;
    sWw[i] = dwc_w[c*9 + k];
  }
  __syncthreads();

  const int c0 = (t & 7) * 8;      // fixed channel block per thread
  float wreg[9][8], breg[8];
  #pragma unroll
  for (int k = 0; k < 9; ++k) {
    *reinterpret_cast<float4*>(&wreg[k][0]) = *reinterpret_cast<const float4*>(&sWw[k*64 + c0]);
    *reinterpret_cast<float4*>(&wreg[k][4]) = *reinterpret_cast<const float4*>(&sWw[k*64 + c0 + 4]);
  }
  *reinterpret_cast<float4*>(&breg[0]) = *reinterpret_cast<const float4*>(dwc_b + c0);
  *reinterpret_cast<float4*>(&breg[4]) = *reinterpret_cast<const float4*>(dwc_b + c0 + 4);

  const u16* ob = o + (size_t)b * CNc;
  u16* ub = U + (size_t)b * CNc;
  for (int i = t; i < CNc/8; i += 256) {     // 1568 items of 8 channels
    const int n = i >> 3;
    const int y = n / WINc, x = n % WINc;
    float acc[8], vv[8];
    unpack8(*reinterpret_cast<const uint4*>(ob + (size_t)i*8), acc);   // residual
    #pragma unroll
    for (int j = 0; j < 8; ++j) acc[j] += breg[j];                     // + bias
    #pragma unroll
    for (int ky = 0; ky < 3; ++ky) {
      const int yy = y + ky - 1;
      if (yy < 0 || yy >= WINc) continue;
      #pragma unroll
      for (int kx = 0; kx < 3; ++kx) {
        const int xx = x + kx - 1;
        if (xx < 0 || xx >= WINc) continue;
        const int k = ky*3 + kx;
        unpack8(*reinterpret_cast<const uint4*>(&sV[(yy*WINc + xx)*Cc + c0]), vv);
        #pragma unroll
        for (int j = 0; j < 8; ++j) acc[j] = fmaf(wreg[k][j], vv[j], acc[j]);
      }
    }
    *reinterpret_cast<uint4*>(ub + (size_t)i*8) = pack8(acc);
  }
}

// ---------------------------------------------------------------------------
// proj GEMM via MFMA (unchanged, passing)
// ---------------------------------------------------------------------------
__global__ __launch_bounds__(256) void proj_mfma(const u16* __restrict__ U,
                                                 const float* __restrict__ Wp,
                                                 const float* __restrict__ bp,
                                                 u16* __restrict__ oproj)
{
  __shared__ u16 As[256 * 72];
  __shared__ u16 Bs[64 * 72];
  const int t = threadIdx.x;
  const int m0 = blockIdx.x * 256;
  const int wave = t >> 6, lane = t & 63;
  const int mi = lane & 15, quad = lane >> 4;

  for (int i = t; i < Cc*Cc; i += 256) {
    const int j = i >> 6, c = i & 63;
    Bs[j*72 + c] = f2bb(Wp[i]);
  }
  {
    const int ar = t >> 2, ac = (t & 3) * 16;
    #pragma unroll
    for (int rb = 0; rb < 4; ++rb) {
      const int row = rb*64 + ar;
      const uint4* src = reinterpret_cast<const uint4*>(U + ((size_t)(m0 + row))*64 + ac);
      *reinterpret_cast<uint4*>(&As[row*72 + ac])     = src[0];
      *reinterpret_cast<uint4*>(&As[row*72 + ac + 8]) = src[1];
    }
  }
  __syncthreads();

  v4f acc[4][4];
  #pragma unroll
  for (int a = 0; a < 4; ++a)
    #pragma unroll
    for (int b = 0; b < 4; ++b) acc[a][b] = (v4f){0.f, 0.f, 0.f, 0.f};

  #pragma unroll
  for (int ks = 0; ks < 2; ++ks) {
    v8s af[4], bf[4];
    #pragma unroll
    for (int mt = 0; mt < 4; ++mt)
      af[mt] = *reinterpret_cast<const v8s*>(&As[(wave*64 + mt*16 + mi)*72 + ks*32 + quad*8]);
    #pragma unroll
    for (int nt = 0; nt < 4; ++nt)
      bf[nt] = *reinterpret_cast<const v8s*>(&Bs[(nt*16 + mi)*72 + ks*32 + quad*8]);
    #pragma unroll
    for (int mt = 0; mt < 4; ++mt)
      #pragma unroll
      for (int nt = 0; nt < 4; ++nt)
        acc[mt][nt] = __builtin_amdgcn_mfma_f32_16x16x32_bf16(af[mt], bf[nt], acc[mt][nt], 0, 0, 0);
  }

  #pragma unroll
  for (int nt = 0; nt < 4; ++nt) {
    const int col = nt*16 + mi;
    const float bc = bp[col];
    #pragma unroll
    for (int mt = 0; mt < 4; ++mt) {
      #pragma unroll
      for (int r = 0; r < 4; ++r) {
        const int row = m0 + wave*64 + mt*16 + quad*4 + r;
        oproj[(size_t)row * 64 + col] = f2bb(acc[mt][nt][r] + bc);
      }
    }
  }
}

// ---------------------------------------------------------------------------
// adjacency GEMM via MFMA, split-K(8), 128x128 tiles + global_load_lds
// (unchanged, passing)
// ---------------------------------------------------------------------------
__global__ __launch_bounds__(256) void gemm_adj_mfma(const u16* __restrict__ Amat,
                                                     const u16* __restrict__ BmatB,
                                                     float* __restrict__ part)
{
  constexpr int K = CNc, Kc = CNc/8;   // 1568 = 49*32
  __shared__ u16 As[128 * 32];
  __shared__ u16 Bs[128 * 32];
  const int t = threadIdx.x;
  const int n0 = blockIdx.x * 128, m0 = blockIdx.y * 128;
  const int kbeg = blockIdx.z * Kc;
  const int wave = t >> 6, lane = t & 63;
  const int wm = wave >> 1, wn = wave & 1;
  const int mi = lane & 15, quad = lane >> 4;

  v4f acc[4][4];
  #pragma unroll
  for (int a = 0; a < 4; ++a)
    #pragma unroll
    for (int b = 0; b < 4; ++b) acc[a][b] = (v4f){0.f, 0.f, 0.f, 0.f};

  const int rs = wave*32 + (lane >> 2);
  const int cs = (lane & 3) * 8;
  const u16* ga0 = Amat + (size_t)(m0 + rs) * K + kbeg + cs;
  const u16* ga1 = Amat + (size_t)(m0 + rs + 16) * K + kbeg + cs;
  const u16* gb0 = BmatB + (size_t)(n0 + rs) * K + kbeg + cs;
  const u16* gb1 = BmatB + (size_t)(n0 + rs + 16) * K + kbeg + cs;
  u16* la0 = &As[(wave*32)      * 32];
  u16* la1 = &As[(wave*32 + 16) * 32];
  u16* lb0 = &Bs[(wave*32)      * 32];
  u16* lb1 = &Bs[(wave*32 + 16) * 32];

  for (int kt = 0; kt < Kc; kt += 32) {
    gl_lds16(ga0 + kt, la0);
    gl_lds16(ga1 + kt, la1);
    gl_lds16(gb0 + kt, lb0);
    gl_lds16(gb1 + kt, lb1);
    __syncthreads();

    v8s af[4], bf[4];
    #pragma unroll
    for (int mt = 0; mt < 4; ++mt)
      af[mt] = *reinterpret_cast<const v8s*>(&As[(wm*64 + mt*16 + mi)*32 + quad*8]);
    #pragma unroll
    for (int nt = 0; nt < 4; ++nt)
      bf[nt] = *reinterpret_cast<const v8s*>(&Bs[(wn*64 + nt*16 + mi)*32 + quad*8]);
    #pragma unroll
    for (int mt = 0; mt < 4; ++mt)
      #pragma unroll
      for (int nt = 0; nt < 4; ++nt)
        acc[mt][nt] = __builtin_amdgcn_mfma_f32_16x16x32_bf16(af[mt], bf[nt], acc[mt][nt], 0, 0, 0);
    __syncthreads();
  }

  const size_t zoff = (size_t)blockIdx.z * B3c * 256;
  #pragma unroll
  for (int nt = 0; nt < 4; ++nt) {
    const int col = n0 + wn*64 + nt*16 + mi;
    #pragma unroll
    for (int mt = 0; mt < 4; ++mt) {
      #pragma unroll
      for (int r = 0; r < 4; ++r) {
        const int row = m0 + wm*64 + mt*16 + quad*4 + r;
        part[zoff + (size_t)row * 256 + col] = acc[mt][nt][r];
      }
    }
  }
}

__global__ __launch_bounds__(256) void reduce_bias_kernel(const float* __restrict__ part,
                                                          const float* __restrict__ bias,
                                                          float* __restrict__ outp)
{
  const int idx = blockIdx.x * 256 + threadIdx.x;   // 768*256 exact
  const int n = idx & 255;
  float acc = bias[n];
  #pragma unroll
  for (int s = 0; s < 8; ++s) acc += part[(size_t)s * B3c * 256 + idx];
  outp[idx] = acc;                                  // fp32 output
}

// ---------------------------------------------------------------------------
extern "C" void kernel_launch(void* const* d_in, const int* in_sizes, int n_in,
                              void* d_out, int out_size, void* d_ws, size_t ws_size,
                              hipStream_t stream)
{
  auto in = [&](int i){ return reinterpret_cast<const float*>(d_in[i]); };
  const float *X = in(0), *We = in(1), *be = in(2), *Wq = in(3), *Wp = in(4), *bp = in(5),
              *dww = in(6), *dwb = in(7), *anb = in(8), *nab = in(9), *ahb = in(10), *awb = in(11),
              *hab = in(12), *wab = in(13), *Wadj = in(14), *badj = in(15),
              *W1 = in(16), *b1 = in(17), *W2 = in(18), *b2 = in(19);
  float* out = reinterpret_cast<float*>(d_out);
  char* w = reinterpret_cast<char*>(d_ws);

  const size_t TOK = (size_t)B3c * CNc;          // 9,633,792 elements
  u16* xt = reinterpret_cast<u16*>(w);            // slot0: xt -> o -> oproj
  u16* qh = reinterpret_cast<u16*>(w + TOK*2);    // slot1: We_bf[0:] -> q head-major -> U
  u16* kh = reinterpret_cast<u16*>(w + TOK*4);    // slot2: We_bf[..] -> k head-major -> part
  u16* vb = reinterpret_cast<u16*>(w + TOK*6);    // slot3: v token-major
  float* pb = reinterpret_cast<float*>(w + TOK*8);
  float* ab = pb + NHc*Ac*Nc;
  u16* WadjB = reinterpret_cast<u16*>(ab + NHc*Ac*Nc);   // 6.4 MB, persistent
  u16* XB  = WadjB + WadjN;                       // 2.0 MB, persistent (spare region)
  u16* W1B = XB + XN;                             // 0.66 MB, persistent
  u16* W2B = W1B + W1N;                           // 64 KB, persistent
  u16* H   = W2B + W2N;                           // 0.39 MB, persistent (written early, read last)
  u16* WeB = qh;                                  // 32.1 MB spans slot1+slot2 (38.5 MB)
  u16* U = qh;                                    // alias: qh dead after attn
  float* part = reinterpret_cast<float*>(kh);     // alias: kh dead after attn
  // total ws use: ~87.2 MB (<= 93.6 MB proven in R3)

  conv_bias_kernel<<<dim3(CONVB + BIASB), 256, 0, stream>>>(
      We, X, Wadj, W1, W2, WeB, XB, WadjB, W1B, W2B,
      anb, nab, ahb, awb, hab, wab, pb, ab);
  gemm_embed_mlp1<<<dim3(100, B3c/128), 256, 0, stream>>>(XB, WeB, W1B, be, b1, xt, H);
  qkv_mfma<<<dim3((B3c*Nc)/256), 256, 0, stream>>>(xt, Wq, qh, kh, vb);
  attn_kernel<<<dim3(B3c*NHc), 256, 0, stream>>>(qh, kh, vb, pb, ab, xt /*o*/);
  dwc_kernel<<<dim3(B3c), 256, 0, stream>>>(xt /*o*/, vb, dww, dwb, U);
  proj_mfma<<<dim3((B3c*Nc)/256), 256, 0, stream>>>(U, Wp, bp, xt /*oproj*/);
  gemm_adj_mfma<<<dim3(256/128, B3c/128, 8), 256, 0, stream>>>(xt /*oproj*/, WadjB, part);
  reduce_bias_kernel<<<dim3((B3c*256)/256), 256, 0, stream>>>(part, badj, out + 3*Bn*128);
  mlp2_mfma<<<dim3(B3c/128), 256, 0, stream>>>(H, W2B, b2, out);
}

// Round 14
// 416.101 us; speedup vs baseline: 1.0351x; 1.0009x over previous
//
#include <hip/hip_runtime.h>

using u16 = unsigned short;
using u32 = unsigned int;

constexpr int Bn   = 256;
constexpr int Dd   = 1280;
constexpr int Cc   = 64;
constexpr int WINc = 14;
constexpr int NHc  = 8;
constexpr int Ac   = 49;
constexpr int Nc   = WINc * WINc;   // 196
constexpr int HDc  = Cc / NHc;      // 8
constexpr int B3c  = 3 * Bn;        // 768
constexpr int CNc  = Cc * Nc;       // 12544

typedef __attribute__((ext_vector_type(8))) short v8s;   // 8 bf16 = 4 VGPRs
typedef __attribute__((ext_vector_type(4))) float v4f;
typedef __attribute__((ext_vector_type(2))) float v2f;   // packed fp32 (v_pk_*)

// bf16 helpers: inputs fp32, workspace intermediates bf16, OUTPUT fp32.
__device__ __forceinline__ float bflo(u32 u){ union{u32 x; float f;} c; c.x = u << 16; return c.f; }
__device__ __forceinline__ float bfhi(u32 u){ union{u32 x; float f;} c; c.x = u & 0xffff0000u; return c.f; }
__device__ __forceinline__ float bfs(u16 h){ union{u32 x; float f;} c; c.x = ((u32)h) << 16; return c.f; }
__device__ __forceinline__ u16 f2bb(float f){
  u32 u = __float_as_uint(f);
  u32 r = (u + 0x7fffu + ((u >> 16) & 1u)) >> 16;
  return (u16)r;
}
__device__ __forceinline__ void unpack8(uint4 u, float* dst){
  dst[0]=bflo(u.x); dst[1]=bfhi(u.x); dst[2]=bflo(u.y); dst[3]=bfhi(u.y);
  dst[4]=bflo(u.z); dst[5]=bfhi(u.z); dst[6]=bflo(u.w); dst[7]=bfhi(u.w);
}
__device__ __forceinline__ uint4 pack8(const float* s){
  uint4 r;
  r.x = (u32)f2bb(s[0]) | ((u32)f2bb(s[1]) << 16);
  r.y = (u32)f2bb(s[2]) | ((u32)f2bb(s[3]) << 16);
  r.z = (u32)f2bb(s[4]) | ((u32)f2bb(s[5]) << 16);
  r.w = (u32)f2bb(s[6]) | ((u32)f2bb(s[7]) << 16);
  return r;
}

// raw hardware exp2: single v_exp_f32, no libm denormal guard (args bounded here)
__device__ __forceinline__ float hexp2(float x){ return __builtin_amdgcn_exp2f(x); }

// async global->LDS, 16B per lane; LDS dest = wave-uniform base + lane*16
__device__ __forceinline__ void gl_lds16(const u16* g, u16* l){
  __builtin_amdgcn_global_load_lds(
      (const __attribute__((address_space(1))) unsigned int*)g,
      (__attribute__((address_space(3))) unsigned int*)l,
      16, 0, 0);
}

// ---------------------------------------------------------------------------
// One-time fp32->bf16 conversion of W_embed, X, W_adj, W1, W2,
// PLUS (fused) position-bias precompute. Biases pre-scaled by log2(e) so
// attn uses hw exp2 (one fma + v_exp per score).
// ---------------------------------------------------------------------------
constexpr int WeN   = 12544 * 1280;   // 16,056,320
constexpr int XN    = 768 * 1280;     //    983,040
constexpr int WadjN = 256 * CNc;      //  3,211,264
constexpr int W1N   = 256 * 1280;     //    327,680
constexpr int W2N   = 128 * 256;      //     32,768
constexpr int CONVB = (WeN + XN + WadjN + W1N + W2N) / (256*8);   // 10064
constexpr int BIASB = (2 * NHc * Ac * Nc + 255) / 256;            // 601
__global__ __launch_bounds__(256) void conv_bias_kernel(const float* __restrict__ We,
                                                        const float* __restrict__ X,
                                                        const float* __restrict__ Wadj,
                                                        const float* __restrict__ W1,
                                                        const float* __restrict__ W2,
                                                        u16* __restrict__ WeB,
                                                        u16* __restrict__ XB,
                                                        u16* __restrict__ WadjB,
                                                        u16* __restrict__ W1B,
                                                        u16* __restrict__ W2B,
                                                        const float* __restrict__ an, const float* __restrict__ na,
                                                        const float* __restrict__ ah, const float* __restrict__ aw,
                                                        const float* __restrict__ ha, const float* __restrict__ wa,
                                                        float* __restrict__ pb, float* __restrict__ ab)
{
  if (blockIdx.x >= CONVB) {
    // ---- bias path (math identical; output scaled by LOG2E) ----
    constexpr float LOG2E = 1.4426950408889634f;
    const int total = NHc * Ac * Nc;   // 76832
    int idx = (blockIdx.x - CONVB) * 256 + threadIdx.x;
    if (idx >= 2 * total) return;
    const bool isab = idx >= total;
    const int r = isab ? idx - total : idx;
    const int h = r / (Ac * Nc);
    const int r2 = r % (Ac * Nc);
    int a, n;
    if (isab) { n = r2 / Ac; a = r2 % Ac; } else { a = r2 / Nc; n = r2 % Nc; }
    const int y = n / WINc, x = n % WINc;
    float sy = fminf(fmaxf(0.5f * y - 0.25f, 0.f), 6.f);
    float sx = fminf(fmaxf(0.5f * x - 0.25f, 0.f), 6.f);
    const int y0 = (int)sy, x0 = (int)sx;
    const float wy = sy - y0, wx = sx - x0;
    const int y1 = (y0 + 1 < 6) ? y0 + 1 : 6;
    const int x1 = (x0 + 1 < 6) ? x0 + 1 : 6;
    const float* src = (isab ? na : an) + (h * Ac + a) * 49;
    const float v00 = src[y0*7 + x0], v01 = src[y0*7 + x1];
    const float v10 = src[y1*7 + x0], v11 = src[y1*7 + x1];
    const float bi = (1.f - wy) * ((1.f - wx) * v00 + wx * v01)
                   + wy * ((1.f - wx) * v10 + wx * v11);
    if (!isab) pb[((size_t)h*Nc + n)*Ac + a] = (bi + ah[(h*Ac + a)*WINc + y] + aw[(h*Ac + a)*WINc + x]) * LOG2E;
    else       ab[((size_t)h*Ac + a)*Nc + n] = (bi + ha[(h*WINc + y)*Ac + a] + wa[(h*WINc + x)*Ac + a]) * LOG2E;
    return;
  }
  // ---- conv path ----
  const size_t idx = ((size_t)blockIdx.x * 256 + threadIdx.x) * 8;
  const float* src; u16* dst;
  if (idx < (size_t)WeN)                          { src = We + idx;                         dst = WeB + idx; }
  else if (idx < (size_t)WeN + XN)                { src = X + (idx - WeN);                  dst = XB + (idx - WeN); }
  else if (idx < (size_t)WeN + XN + WadjN)        { src = Wadj + (idx - WeN - XN);          dst = WadjB + (idx - WeN - XN); }
  else if (idx < (size_t)WeN + XN + WadjN + W1N)  { src = W1 + (idx - WeN - XN - WadjN);    dst = W1B + (idx - WeN - XN - WadjN); }
  else                                            { src = W2 + (idx - WeN - XN - WadjN - W1N); dst = W2B + (idx - WeN - XN - WadjN - W1N); }
  float v[8];
  *reinterpret_cast<float4*>(&v[0]) = *reinterpret_cast<const float4*>(src);
  *reinterpret_cast<float4*>(&v[4]) = *reinterpret_cast<const float4*>(src + 4);
  *reinterpret_cast<uint4*>(dst) = pack8(v);
}

// ---------------------------------------------------------------------------
// MERGED embed + mlp1 GEMM (same K=1280, same A=XB): blocks x<98 compute
// embed (B=WeB, N=12544, no tanh); x>=98 compute mlp1 (B=W1B, N=256, tanh).
// m97-style global_load_lds staging, 128x128 tile, 2-barrier K loop.
// ---------------------------------------------------------------------------
__global__ __launch_bounds__(256) void gemm_embed_mlp1(const u16* __restrict__ XB,
                                                       const u16* __restrict__ WeB,
                                                       const u16* __restrict__ W1B,
                                                       const float* __restrict__ be,
                                                       const float* __restrict__ b1,
                                                       u16* __restrict__ xt,
                                                       u16* __restrict__ H)
{
  constexpr int KK = Dd;
  __shared__ u16 As[128 * 32];
  __shared__ u16 Bs[128 * 32];
  const int t = threadIdx.x;
  const bool mlp = blockIdx.x >= 98;
  const int n0 = (mlp ? (blockIdx.x - 98) : blockIdx.x) * 128;
  const int m0 = blockIdx.y * 128;
  const u16* Bmat = mlp ? W1B : WeB;
  const float* bias = mlp ? b1 : be;
  u16* Cmat = mlp ? H : xt;
  const int NN = mlp ? 256 : CNc;
  const int wave = t >> 6, lane = t & 63;
  const int wm = wave >> 1, wn = wave & 1;
  const int mi = lane & 15, quad = lane >> 4;

  v4f acc[4][4];
  #pragma unroll
  for (int a = 0; a < 4; ++a)
    #pragma unroll
    for (int b = 0; b < 4; ++b) acc[a][b] = (v4f){0.f, 0.f, 0.f, 0.f};

  const int rs = wave*32 + (lane >> 2);
  const int cs = (lane & 3) * 8;
  const u16* ga0 = XB + (size_t)(m0 + rs) * KK + cs;
  const u16* ga1 = XB + (size_t)(m0 + rs + 16) * KK + cs;
  const u16* gb0 = Bmat + (size_t)(n0 + rs) * KK + cs;
  const u16* gb1 = Bmat + (size_t)(n0 + rs + 16) * KK + cs;
  u16* la0 = &As[(wave*32)      * 32];
  u16* la1 = &As[(wave*32 + 16) * 32];
  u16* lb0 = &Bs[(wave*32)      * 32];
  u16* lb1 = &Bs[(wave*32 + 16) * 32];

  for (int kt = 0; kt < KK; kt += 32) {
    gl_lds16(ga0 + kt, la0);
    gl_lds16(ga1 + kt, la1);
    gl_lds16(gb0 + kt, lb0);
    gl_lds16(gb1 + kt, lb1);
    __syncthreads();

    v8s af[4], bf[4];
    #pragma unroll
    for (int mt = 0; mt < 4; ++mt)
      af[mt] = *reinterpret_cast<const v8s*>(&As[(wm*64 + mt*16 + mi)*32 + quad*8]);
    #pragma unroll
    for (int nt = 0; nt < 4; ++nt)
      bf[nt] = *reinterpret_cast<const v8s*>(&Bs[(wn*64 + nt*16 + mi)*32 + quad*8]);
    #pragma unroll
    for (int mt = 0; mt < 4; ++mt)
      #pragma unroll
      for (int nt = 0; nt < 4; ++nt)
        acc[mt][nt] = __builtin_amdgcn_mfma_f32_16x16x32_bf16(af[mt], bf[nt], acc[mt][nt], 0, 0, 0);
    __syncthreads();
  }

  #pragma unroll
  for (int nt = 0; nt < 4; ++nt) {
    const int col = n0 + wn*64 + nt*16 + mi;
    const float bc = bias[col];
    #pragma unroll
    for (int mt = 0; mt < 4; ++mt) {
      #pragma unroll
      for (int r = 0; r < 4; ++r) {
        const int row = m0 + wm*64 + mt*16 + quad*4 + r;
        float val = acc[mt][nt][r] + bc;
        if (mlp) val = tanhf(val);
        Cmat[(size_t)row * NN + col] = f2bb(val);
      }
    }
  }
}

// ---------------------------------------------------------------------------
// MERGED tail: blocks < B3c do reduce_bias (split-K partial sum + bias);
// blocks >= B3c (6 of them) do mlp2. Disjoint outputs, block-uniform branch.
// ---------------------------------------------------------------------------
__global__ __launch_bounds__(256) void tail_kernel(const float* __restrict__ part,
                                                   const float* __restrict__ badj,
                                                   float* __restrict__ outadj,
                                                   const u16* __restrict__ H,
                                                   const u16* __restrict__ W2B,
                                                   const float* __restrict__ b2,
                                                   float* __restrict__ outp)
{
  __shared__ u16 As[128 * 40];
  __shared__ u16 Bs[128 * 40];
  const int t = threadIdx.x;
  if (blockIdx.x < B3c) {
    // ---- reduce_bias path (byte-identical math) ----
    const int idx = blockIdx.x * 256 + t;           // 768*256 exact
    const int n = idx & 255;
    float acc = badj[n];
    #pragma unroll
    for (int s = 0; s < 8; ++s) acc += part[(size_t)s * B3c * 256 + idx];
    outadj[idx] = acc;
    return;
  }
  // ---- mlp2 path (byte-identical math) ----
  const int m0 = (blockIdx.x - B3c) * 128;
  const int wave = t >> 6, lane = t & 63;
  const int wm = wave >> 1, wn = wave & 1;
  const int mi = lane & 15, quad = lane >> 4;
  const int srow = t >> 1, scol = (t & 1) * 16;

  v4f acc[4][4];
  #pragma unroll
  for (int a = 0; a < 4; ++a)
    #pragma unroll
    for (int b = 0; b < 4; ++b) acc[a][b] = (v4f){0.f, 0.f, 0.f, 0.f};

  for (int kt = 0; kt < 256; kt += 32) {
    const u16* ap = H + (size_t)(m0 + srow) * 256 + kt + scol;
    *reinterpret_cast<uint4*>(&As[srow*40 + scol])     = *reinterpret_cast<const uint4*>(ap);
    *reinterpret_cast<uint4*>(&As[srow*40 + scol + 8]) = *reinterpret_cast<const uint4*>(ap + 8);
    const u16* bp = W2B + (size_t)srow * 256 + kt + scol;
    *reinterpret_cast<uint4*>(&Bs[srow*40 + scol])     = *reinterpret_cast<const uint4*>(bp);
    *reinterpret_cast<uint4*>(&Bs[srow*40 + scol + 8]) = *reinterpret_cast<const uint4*>(bp + 8);
    __syncthreads();

    v8s af[4], bf[4];
    #pragma unroll
    for (int mt = 0; mt < 4; ++mt)
      af[mt] = *reinterpret_cast<const v8s*>(&As[(wm*64 + mt*16 + mi)*40 + quad*8]);
    #pragma unroll
    for (int nt = 0; nt < 4; ++nt)
      bf[nt] = *reinterpret_cast<const v8s*>(&Bs[(wn*64 + nt*16 + mi)*40 + quad*8]);
    #pragma unroll
    for (int mt = 0; mt < 4; ++mt)
      #pragma unroll
      for (int nt = 0; nt < 4; ++nt)
        acc[mt][nt] = __builtin_amdgcn_mfma_f32_16x16x32_bf16(af[mt], bf[nt], acc[mt][nt], 0, 0, 0);
    __syncthreads();
  }

  #pragma unroll
  for (int nt = 0; nt < 4; ++nt) {
    const int col = wn*64 + nt*16 + mi;   // 0..127
    const float bc = b2[col];
    #pragma unroll
    for (int mt = 0; mt < 4; ++mt) {
      #pragma unroll
      for (int r = 0; r < 4; ++r) {
        const int row = m0 + wm*64 + mt*16 + quad*4 + r;
        const int bi = row / 3, s = row - bi * 3;
        outp[(size_t)s * (Bn*128) + (size_t)bi * 128 + col] = acc[mt][nt][r] + bc;
      }
    }
  }
}

// ---------------------------------------------------------------------------
// qkv via MFMA — 3 segments LOOPED in one block (grid 588, R12 version)
// ---------------------------------------------------------------------------
__global__ __launch_bounds__(256) void qkv_mfma(const u16* __restrict__ xt, const float* __restrict__ Wqkv,
                                                u16* __restrict__ qh, u16* __restrict__ kh, u16* __restrict__ vb)
{
  __shared__ u16 As[256 * 72];
  __shared__ u16 Bs[64 * 72];
  const int t = threadIdx.x;
  const int m0 = blockIdx.x * 256;
  const int wave = t >> 6, lane = t & 63;
  const int mi = lane & 15, quad = lane >> 4;

  {
    const int ar = t >> 2, ac = (t & 3) * 16;
    #pragma unroll
    for (int rb = 0; rb < 4; ++rb) {
      const int row = rb*64 + ar;
      const uint4* src = reinterpret_cast<const uint4*>(xt + ((size_t)(m0 + row))*64 + ac);
      *reinterpret_cast<uint4*>(&As[row*72 + ac])     = src[0];
      *reinterpret_cast<uint4*>(&As[row*72 + ac + 8]) = src[1];
    }
  }
  __syncthreads();   // As visible

  v8s af[2][4];      // seg-invariant A fragments
  #pragma unroll
  for (int ks = 0; ks < 2; ++ks)
    #pragma unroll
    for (int mt = 0; mt < 4; ++mt)
      af[ks][mt] = *reinterpret_cast<const v8s*>(&As[(wave*64 + mt*16 + mi)*72 + ks*32 + quad*8]);

  #pragma unroll 1
  for (int seg = 0; seg < 3; ++seg) {
    if (seg) __syncthreads();          // prior segment's Bs reads complete
    for (int i = t; i < Cc*Cc; i += 256) {
      const int j = i >> 6, c = i & 63;
      Bs[j*72 + c] = f2bb(Wqkv[(size_t)(seg*64 + j)*64 + c]);
    }
    __syncthreads();                   // Bs visible

    v4f acc[4][4];
    #pragma unroll
    for (int a = 0; a < 4; ++a)
      #pragma unroll
      for (int b = 0; b < 4; ++b) acc[a][b] = (v4f){0.f, 0.f, 0.f, 0.f};

    #pragma unroll
    for (int ks = 0; ks < 2; ++ks) {
      v8s bf[4];
      #pragma unroll
      for (int nt = 0; nt < 4; ++nt)
        bf[nt] = *reinterpret_cast<const v8s*>(&Bs[(nt*16 + mi)*72 + ks*32 + quad*8]);
      #pragma unroll
      for (int mt = 0; mt < 4; ++mt)
        #pragma unroll
        for (int nt = 0; nt < 4; ++nt)
          acc[mt][nt] = __builtin_amdgcn_mfma_f32_16x16x32_bf16(af[ks][mt], bf[nt], acc[mt][nt], 0, 0, 0);
    }

    u16* hm = (seg == 0) ? qh : kh;
    #pragma unroll
    for (int nt = 0; nt < 4; ++nt) {
      const int col = nt*16 + mi;
      const int h = col >> 3, d = col & 7;
      #pragma unroll
      for (int mt = 0; mt < 4; ++mt) {
        #pragma unroll
        for (int r = 0; r < 4; ++r) {
          const int row = m0 + wave*64 + mt*16 + quad*4 + r;
          const u16 val = f2bb(acc[mt][nt][r]);
          if (seg < 2) {
            const int b = row / Nc, n = row - b * Nc;
            hm[((size_t)(b*NHc + h)*Nc + n)*8 + d] = val;
          } else {
            vb[(size_t)row * 64 + col] = val;
          }
        }
      }
    }
  }
}

// ---------------------------------------------------------------------------
// fused agent attention v6 + hw-exp2 + XCD-coherent block decode:
//   h = bh / 768, b = bh % 768 (was b = bh>>3, h = bh&7). Since 768 % 8 == 0,
//   all 8 head-blocks of batch b land on the SAME XCD (bh%8 == b%8 for all h)
//   -> each 128-B v-line (holds all 8 heads of a token) is fetched once per
//   L2 instead of 8x. Bijective remap; math unchanged.
// ---------------------------------------------------------------------------
__global__ __launch_bounds__(256) void attn_kernel(const u16* __restrict__ qh, const u16* __restrict__ kh,
                                                   const u16* __restrict__ v,
                                                   const float* __restrict__ pb, const float* __restrict__ ab,
                                                   u16* __restrict__ o)
{
  __shared__ float sU[Nc*10];        // union: sQ (Nc*8) then sPart (Nc*9 used)
  __shared__ float sK[Nc*8], sV[Nc*8];
  __shared__ float sAg[Ac*8], sAV[Ac*8];
  const int bhid = blockIdx.x;
  const int h = bhid / B3c, b = bhid - h * B3c;   // XCD-coherent decode
  const int bh = b * NHc + h;                     // data index (layout unchanged)
  const int t = threadIdx.x;
  const float scale2 = 0.3535533905932738f * 1.4426950408889634f;  // scale * log2(e)

  float qreg[8];
  if (t < Nc) {
    const size_t base = ((size_t)bh * Nc + t) * 8;
    unpack8(*reinterpret_cast<const uint4*>(qh + base), qreg);
    #pragma unroll
    for (int d = 0; d < 8; ++d) sU[t*8 + d] = qreg[d];   // sQ view
    unpack8(*reinterpret_cast<const uint4*>(kh + base), &sK[t*8]);
    unpack8(*reinterpret_cast<const uint4*>(v + ((size_t)b*Nc + t)*64 + h*8), &sV[t*8]);
  }
  __syncthreads();

  for (int i = t; i < Ac*8; i += 256) {
    const int a = i >> 3, d = i & 7;
    const int ay = a / 7, ax = a % 7;
    const int n00 = (ay * 2) * WINc + ax * 2;
    sAg[i] = 0.25f * (sU[n00*8+d] + sU[(n00+1)*8+d] + sU[(n00+WINc)*8+d] + sU[(n00+WINc+1)*8+d]);
  }
  __syncthreads();   // sQ reads done; sU becomes sPart

  // stage 1: thread t<196 -> quarter qd, agent a; 2-way unrolled
  if (t < Nc) {
    const int qd = t / Ac, a = t - qd * Ac;
    const int nb = qd * Ac;
    v2f g2[4];
    #pragma unroll
    for (int d2 = 0; d2 < 4; ++d2) g2[d2] = *reinterpret_cast<const v2f*>(&sAg[a*8 + d2*2]);
    const float* pbr = pb + ((size_t)h*Nc + nb)*Ac + a;   // step Ac per j
    float l0 = 0.f, l1 = 0.f;
    v2f avA[4] = {}, avB[4] = {};
    for (int j = 0; j < 48; j += 2) {
      const v2f* k0 = reinterpret_cast<const v2f*>(&sK[(nb + j)*8]);
      const v2f* k1 = reinterpret_cast<const v2f*>(&sK[(nb + j + 1)*8]);
      v2f sa = (g2[0]*k0[0] + g2[1]*k0[1]) + (g2[2]*k0[2] + g2[3]*k0[3]);
      v2f sb = (g2[0]*k1[0] + g2[1]*k1[1]) + (g2[2]*k1[2] + g2[3]*k1[3]);
      const float e0 = hexp2(fmaf(sa.x + sa.y, scale2, pbr[j*Ac]));
      const float e1 = hexp2(fmaf(sb.x + sb.y, scale2, pbr[(j+1)*Ac]));
      l0 += e0; l1 += e1;
      const v2f* v0 = reinterpret_cast<const v2f*>(&sV[(nb + j)*8]);
      const v2f* v1 = reinterpret_cast<const v2f*>(&sV[(nb + j + 1)*8]);
      const v2f e02 = {e0, e0}, e12 = {e1, e1};
      #pragma unroll
      for (int d2 = 0; d2 < 4; ++d2) { avA[d2] += e02 * v0[d2]; avB[d2] += e12 * v1[d2]; }
    }
    { // tail j = 48
      const v2f* k0 = reinterpret_cast<const v2f*>(&sK[(nb + 48)*8]);
      v2f sa = (g2[0]*k0[0] + g2[1]*k0[1]) + (g2[2]*k0[2] + g2[3]*k0[3]);
      const float e0 = hexp2(fmaf(sa.x + sa.y, scale2, pbr[48*Ac]));
      l0 += e0;
      const v2f* v0 = reinterpret_cast<const v2f*>(&sV[(nb + 48)*8]);
      const v2f e02 = {e0, e0};
      #pragma unroll
      for (int d2 = 0; d2 < 4; ++d2) avA[d2] += e02 * v0[d2];
    }
    float* pp = &sU[t*9];            // sPart view
    pp[0] = l0 + l1;
    #pragma unroll
    for (int d2 = 0; d2 < 4; ++d2) {
      const v2f m = avA[d2] + avB[d2];
      pp[1+d2*2] = m.x; pp[2+d2*2] = m.y;
    }
  }
  __syncthreads();

  if (t < Ac) {
    float L = 0.f, av[8] = {};
    #pragma unroll
    for (int p = 0; p < 4; ++p) {
      const float* pp = &sU[(p*Ac + t)*9];
      L += pp[0];
      #pragma unroll
      for (int d = 0; d < 8; ++d) av[d] += pp[1+d];
    }
    const float inv = 1.f / L;
    #pragma unroll
    for (int d = 0; d < 8; ++d) sAV[t*8 + d] = av[d] * inv;
  }
  __syncthreads();

  // stage 2: thread = token n; 2-way unrolled over agents
  if (t < Nc) {
    v2f q2[4];
    #pragma unroll
    for (int d2 = 0; d2 < 4; ++d2) q2[d2] = (v2f){qreg[d2*2], qreg[d2*2+1]};
    const float* abr = ab + (size_t)h*Ac*Nc + t;          // step Nc per a
    float l0 = 0.f, l1 = 0.f;
    v2f oA[4] = {}, oB[4] = {};
    for (int a = 0; a < 48; a += 2) {
      const v2f* g0 = reinterpret_cast<const v2f*>(&sAg[a*8]);
      const v2f* g1 = reinterpret_cast<const v2f*>(&sAg[(a+1)*8]);
      v2f sa = (q2[0]*g0[0] + q2[1]*g0[1]) + (q2[2]*g0[2] + q2[3]*g0[3]);
      v2f sb = (q2[0]*g1[0] + q2[1]*g1[1]) + (q2[2]*g1[2] + q2[3]*g1[3]);
      const float e0 = hexp2(fmaf(sa.x + sa.y, scale2, abr[a*Nc]));
      const float e1 = hexp2(fmaf(sb.x + sb.y, scale2, abr[(a+1)*Nc]));
      l0 += e0; l1 += e1;
      const v2f* a0 = reinterpret_cast<const v2f*>(&sAV[a*8]);
      const v2f* a1 = reinterpret_cast<const v2f*>(&sAV[(a+1)*8]);
      const v2f e02 = {e0, e0}, e12 = {e1, e1};
      #pragma unroll
      for (int d2 = 0; d2 < 4; ++d2) { oA[d2] += e02 * a0[d2]; oB[d2] += e12 * a1[d2]; }
    }
    { // tail a = 48
      const v2f* g0 = reinterpret_cast<const v2f*>(&sAg[48*8]);
      v2f sa = (q2[0]*g0[0] + q2[1]*g0[1]) + (q2[2]*g0[2] + q2[3]*g0[3]);
      const float e0 = hexp2(fmaf(sa.x + sa.y, scale2, abr[48*Nc]));
      l0 += e0;
      const v2f* a0 = reinterpret_cast<const v2f*>(&sAV[48*8]);
      const v2f e02 = {e0, e0};
      #pragma unroll
      for (int d2 = 0; d2 < 4; ++d2) oA[d2] += e02 * a0[d2];
    }
    const float inv = 1.f / (l0 + l1);
    float o8[8];
    #pragma unroll
    for (int d2 = 0; d2 < 4; ++d2) {
      const v2f m = oA[d2] + oB[d2];
      o8[d2*2] = m.x * inv; o8[d2*2+1] = m.y * inv;
    }
    *reinterpret_cast<uint4*>(&o[((size_t)b*Nc + t)*64 + h*8]) = pack8(o8);
  }
}

// ---------------------------------------------------------------------------
// dwc 3x3 depthwise + residual, VECTORIZED (R9 version, measured good)
// ---------------------------------------------------------------------------
__global__ __launch_bounds__(256) void dwc_kernel(const u16* __restrict__ o, const u16* __restrict__ v,
                                                  const float* __restrict__ dwc_w, const float* __restrict__ dwc_b,
                                                  u16* __restrict__ U)
{
  __shared__ u16 sV[Nc*Cc];        // 25088 B
  __shared__ float sWw[9*64];      //  2304 B: wT[k][c] = dwc_w[c*9+k]
  const int b = blockIdx.x, t = threadIdx.x;

  const uint2* vsrc = reinterpret_cast<const uint2*>(v + (size_t)b * CNc);
  uint2* sV2 = reinterpret_cast<uint2*>(sV);
  for (int i = t; i < CNc/4; i += 256) sV2[i] = vsrc[i];
  for (int i = t; i < 9*64; i += 256) {
    const int k = i >> 6, c = i & 63;
    sWw[i] = dwc_w[c*9 + k];
  }
  __syncthreads();

  const int c0 = (t & 7) * 8;      // fixed channel block per thread
  float wreg[9][8], breg[8];
  #pragma unroll
  for (int k = 0; k < 9; ++k) {
    *reinterpret_cast<float4*>(&wreg[k][0]) = *reinterpret_cast<const float4*>(&sWw[k*64 + c0]);
    *reinterpret_cast<float4*>(&wreg[k][4]) = *reinterpret_cast<const float4*>(&sWw[k*64 + c0 + 4]);
  }
  *reinterpret_cast<float4*>(&breg[0]) = *reinterpret_cast<const float4*>(dwc_b + c0);
  *reinterpret_cast<float4*>(&breg[4]) = *reinterpret_cast<const float4*>(dwc_b + c0 + 4);

  const u16* ob = o + (size_t)b * CNc;
  u16* ub = U + (size_t)b * CNc;
  for (int i = t; i < CNc/8; i += 256) {     // 1568 items of 8 channels
    const int n = i >> 3;
    const int y = n / WINc, x = n % WINc;
    float acc[8], vv[8];
    unpack8(*reinterpret_cast<const uint4*>(ob + (size_t)i*8), acc);   // residual
    #pragma unroll
    for (int j = 0; j < 8; ++j) acc[j] += breg[j];                     // + bias
    #pragma unroll
    for (int ky = 0; ky < 3; ++ky) {
      const int yy = y + ky - 1;
      if (yy < 0 || yy >= WINc) continue;
      #pragma unroll
      for (int kx = 0; kx < 3; ++kx) {
        const int xx = x + kx - 1;
        if (xx < 0 || xx >= WINc) continue;
        const int k = ky*3 + kx;
        unpack8(*reinterpret_cast<const uint4*>(&sV[(yy*WINc + xx)*Cc + c0]), vv);
        #pragma unroll
        for (int j = 0; j < 8; ++j) acc[j] = fmaf(wreg[k][j], vv[j], acc[j]);
      }
    }
    *reinterpret_cast<uint4*>(ub + (size_t)i*8) = pack8(acc);
  }
}

// ---------------------------------------------------------------------------
// proj GEMM via MFMA (unchanged, passing)
// ---------------------------------------------------------------------------
__global__ __launch_bounds__(256) void proj_mfma(const u16* __restrict__ U,
                                                 const float* __restrict__ Wp,
                                                 const float* __restrict__ bp,
                                                 u16* __restrict__ oproj)
{
  __shared__ u16 As[256 * 72];
  __shared__ u16 Bs[64 * 72];
  const int t = threadIdx.x;
  const int m0 = blockIdx.x * 256;
  const int wave = t >> 6, lane = t & 63;
  const int mi = lane & 15, quad = lane >> 4;

  for (int i = t; i < Cc*Cc; i += 256) {
    const int j = i >> 6, c = i & 63;
    Bs[j*72 + c] = f2bb(Wp[i]);
  }
  {
    const int ar = t >> 2, ac = (t & 3) * 16;
    #pragma unroll
    for (int rb = 0; rb < 4; ++rb) {
      const int row = rb*64 + ar;
      const uint4* src = reinterpret_cast<const uint4*>(U + ((size_t)(m0 + row))*64 + ac);
      *reinterpret_cast<uint4*>(&As[row*72 + ac])     = src[0];
      *reinterpret_cast<uint4*>(&As[row*72 + ac + 8]) = src[1];
    }
  }
  __syncthreads();

  v4f acc[4][4];
  #pragma unroll
  for (int a = 0; a < 4; ++a)
    #pragma unroll
    for (int b = 0; b < 4; ++b) acc[a][b] = (v4f){0.f, 0.f, 0.f, 0.f};

  #pragma unroll
  for (int ks = 0; ks < 2; ++ks) {
    v8s af[4], bf[4];
    #pragma unroll
    for (int mt = 0; mt < 4; ++mt)
      af[mt] = *reinterpret_cast<const v8s*>(&As[(wave*64 + mt*16 + mi)*72 + ks*32 + quad*8]);
    #pragma unroll
    for (int nt = 0; nt < 4; ++nt)
      bf[nt] = *reinterpret_cast<const v8s*>(&Bs[(nt*16 + mi)*72 + ks*32 + quad*8]);
    #pragma unroll
    for (int mt = 0; mt < 4; ++mt)
      #pragma unroll
      for (int nt = 0; nt < 4; ++nt)
        acc[mt][nt] = __builtin_amdgcn_mfma_f32_16x16x32_bf16(af[mt], bf[nt], acc[mt][nt], 0, 0, 0);
  }

  #pragma unroll
  for (int nt = 0; nt < 4; ++nt) {
    const int col = nt*16 + mi;
    const float bc = bp[col];
    #pragma unroll
    for (int mt = 0; mt < 4; ++mt) {
      #pragma unroll
      for (int r = 0; r < 4; ++r) {
        const int row = m0 + wave*64 + mt*16 + quad*4 + r;
        oproj[(size_t)row * 64 + col] = f2bb(acc[mt][nt][r] + bc);
      }
    }
  }
}

// ---------------------------------------------------------------------------
// adjacency GEMM via MFMA, split-K(8), 128x128 tiles + global_load_lds
// (unchanged, passing)
// ---------------------------------------------------------------------------
__global__ __launch_bounds__(256) void gemm_adj_mfma(const u16* __restrict__ Amat,
                                                     const u16* __restrict__ BmatB,
                                                     float* __restrict__ part)
{
  constexpr int K = CNc, Kc = CNc/8;   // 1568 = 49*32
  __shared__ u16 As[128 * 32];
  __shared__ u16 Bs[128 * 32];
  const int t = threadIdx.x;
  const int n0 = blockIdx.x * 128, m0 = blockIdx.y * 128;
  const int kbeg = blockIdx.z * Kc;
  const int wave = t >> 6, lane = t & 63;
  const int wm = wave >> 1, wn = wave & 1;
  const int mi = lane & 15, quad = lane >> 4;

  v4f acc[4][4];
  #pragma unroll
  for (int a = 0; a < 4; ++a)
    #pragma unroll
    for (int b = 0; b < 4; ++b) acc[a][b] = (v4f){0.f, 0.f, 0.f, 0.f};

  const int rs = wave*32 + (lane >> 2);
  const int cs = (lane & 3) * 8;
  const u16* ga0 = Amat + (size_t)(m0 + rs) * K + kbeg + cs;
  const u16* ga1 = Amat + (size_t)(m0 + rs + 16) * K + kbeg + cs;
  const u16* gb0 = BmatB + (size_t)(n0 + rs) * K + kbeg + cs;
  const u16* gb1 = BmatB + (size_t)(n0 + rs + 16) * K + kbeg + cs;
  u16* la0 = &As[(wave*32)      * 32];
  u16* la1 = &As[(wave*32 + 16) * 32];
  u16* lb0 = &Bs[(wave*32)      * 32];
  u16* lb1 = &Bs[(wave*32 + 16) * 32];

  for (int kt = 0; kt < Kc; kt += 32) {
    gl_lds16(ga0 + kt, la0);
    gl_lds16(ga1 + kt, la1);
    gl_lds16(gb0 + kt, lb0);
    gl_lds16(gb1 + kt, lb1);
    __syncthreads();

    v8s af[4], bf[4];
    #pragma unroll
    for (int mt = 0; mt < 4; ++mt)
      af[mt] = *reinterpret_cast<const v8s*>(&As[(wm*64 + mt*16 + mi)*32 + quad*8]);
    #pragma unroll
    for (int nt = 0; nt < 4; ++nt)
      bf[nt] = *reinterpret_cast<const v8s*>(&Bs[(wn*64 + nt*16 + mi)*32 + quad*8]);
    #pragma unroll
    for (int mt = 0; mt < 4; ++mt)
      #pragma unroll
      for (int nt = 0; nt < 4; ++nt)
        acc[mt][nt] = __builtin_amdgcn_mfma_f32_16x16x32_bf16(af[mt], bf[nt], acc[mt][nt], 0, 0, 0);
    __syncthreads();
  }

  const size_t zoff = (size_t)blockIdx.z * B3c * 256;
  #pragma unroll
  for (int nt = 0; nt < 4; ++nt) {
    const int col = n0 + wn*64 + nt*16 + mi;
    #pragma unroll
    for (int mt = 0; mt < 4; ++mt) {
      #pragma unroll
      for (int r = 0; r < 4; ++r) {
        const int row = m0 + wm*64 + mt*16 + quad*4 + r;
        part[zoff + (size_t)row * 256 + col] = acc[mt][nt][r];
      }
    }
  }
}

// ---------------------------------------------------------------------------
extern "C" void kernel_launch(void* const* d_in, const int* in_sizes, int n_in,
                              void* d_out, int out_size, void* d_ws, size_t ws_size,
                              hipStream_t stream)
{
  auto in = [&](int i){ return reinterpret_cast<const float*>(d_in[i]); };
  const float *X = in(0), *We = in(1), *be = in(2), *Wq = in(3), *Wp = in(4), *bp = in(5),
              *dww = in(6), *dwb = in(7), *anb = in(8), *nab = in(9), *ahb = in(10), *awb = in(11),
              *hab = in(12), *wab = in(13), *Wadj = in(14), *badj = in(15),
              *W1 = in(16), *b1 = in(17), *W2 = in(18), *b2 = in(19);
  float* out = reinterpret_cast<float*>(d_out);
  char* w = reinterpret_cast<char*>(d_ws);

  const size_t TOK = (size_t)B3c * CNc;          // 9,633,792 elements
  u16* xt = reinterpret_cast<u16*>(w);            // slot0: xt -> o -> oproj
  u16* qh = reinterpret_cast<u16*>(w + TOK*2);    // slot1: We_bf[0:] -> q head-major -> U
  u16* kh = reinterpret_cast<u16*>(w + TOK*4);    // slot2: We_bf[..] -> k head-major -> part
  u16* vb = reinterpret_cast<u16*>(w + TOK*6);    // slot3: v token-major
  float* pb = reinterpret_cast<float*>(w + TOK*8);
  float* ab = pb + NHc*Ac*Nc;
  u16* WadjB = reinterpret_cast<u16*>(ab + NHc*Ac*Nc);   // 6.4 MB, persistent
  u16* XB  = WadjB + WadjN;                       // 2.0 MB, persistent (spare region)
  u16* W1B = XB + XN;                             // 0.66 MB, persistent
  u16* W2B = W1B + W1N;                           // 64 KB, persistent
  u16* H   = W2B + W2N;                           // 0.39 MB, persistent (written early, read last)
  u16* WeB = qh;                                  // 32.1 MB spans slot1+slot2 (38.5 MB)
  u16* U = qh;                                    // alias: qh dead after attn
  float* part = reinterpret_cast<float*>(kh);     // alias: kh dead after attn
  // total ws use: ~87.2 MB (<= 93.6 MB proven in R3)

  conv_bias_kernel<<<dim3(CONVB + BIASB), 256, 0, stream>>>(
      We, X, Wadj, W1, W2, WeB, XB, WadjB, W1B, W2B,
      anb, nab, ahb, awb, hab, wab, pb, ab);
  gemm_embed_mlp1<<<dim3(100, B3c/128), 256, 0, stream>>>(XB, WeB, W1B, be, b1, xt, H);
  qkv_mfma<<<dim3((B3c*Nc)/256), 256, 0, stream>>>(xt, Wq, qh, kh, vb);
  attn_kernel<<<dim3(B3c*NHc), 256, 0, stream>>>(qh, kh, vb, pb, ab, xt /*o*/);
  dwc_kernel<<<dim3(B3c), 256, 0, stream>>>(xt /*o*/, vb, dww, dwb, U);
  proj_mfma<<<dim3((B3c*Nc)/256), 256, 0, stream>>>(U, Wp, bp, xt /*oproj*/);
  gemm_adj_mfma<<<dim3(256/128, B3c/128, 8), 256, 0, stream>>>(xt /*oproj*/, WadjB, part);
  tail_kernel<<<dim3(B3c + B3c/128), 256, 0, stream>>>(part, badj, out + 3*Bn*128, H, W2B, b2, out);
}

// Round 17
// 415.308 us; speedup vs baseline: 1.0370x; 1.0019x over previous
//
#include <hip/hip_runtime.h>

using u16 = unsigned short;
using u32 = unsigned int;

constexpr int Bn   = 256;
constexpr int Dd   = 1280;
constexpr int Cc   = 64;
constexpr int WINc = 14;
constexpr int NHc  = 8;
constexpr int Ac   = 49;
constexpr int Nc   = WINc * WINc;   // 196
constexpr int HDc  = Cc / NHc;      // 8
constexpr int B3c  = 3 * Bn;        // 768
constexpr int CNc  = Cc * Nc;       // 12544

typedef __attribute__((ext_vector_type(8))) short v8s;   // 8 bf16 = 4 VGPRs
typedef __attribute__((ext_vector_type(4))) float v4f;
typedef __attribute__((ext_vector_type(2))) float v2f;   // packed fp32 (v_pk_*)

// bf16 helpers: inputs fp32, workspace intermediates bf16, OUTPUT fp32.
__device__ __forceinline__ float bflo(u32 u){ union{u32 x; float f;} c; c.x = u << 16; return c.f; }
__device__ __forceinline__ float bfhi(u32 u){ union{u32 x; float f;} c; c.x = u & 0xffff0000u; return c.f; }
__device__ __forceinline__ float bfs(u16 h){ union{u32 x; float f;} c; c.x = ((u32)h) << 16; return c.f; }
__device__ __forceinline__ u16 f2bb(float f){
  u32 u = __float_as_uint(f);
  u32 r = (u + 0x7fffu + ((u >> 16) & 1u)) >> 16;
  return (u16)r;
}
__device__ __forceinline__ void unpack8(uint4 u, float* dst){
  dst[0]=bflo(u.x); dst[1]=bfhi(u.x); dst[2]=bflo(u.y); dst[3]=bfhi(u.y);
  dst[4]=bflo(u.z); dst[5]=bfhi(u.z); dst[6]=bflo(u.w); dst[7]=bfhi(u.w);
}
__device__ __forceinline__ uint4 pack8(const float* s){
  uint4 r;
  r.x = (u32)f2bb(s[0]) | ((u32)f2bb(s[1]) << 16);
  r.y = (u32)f2bb(s[2]) | ((u32)f2bb(s[3]) << 16);
  r.z = (u32)f2bb(s[4]) | ((u32)f2bb(s[5]) << 16);
  r.w = (u32)f2bb(s[6]) | ((u32)f2bb(s[7]) << 16);
  return r;
}

// raw hardware exp2: single v_exp_f32, no libm denormal guard (args bounded here)
__device__ __forceinline__ float hexp2(float x){ return __builtin_amdgcn_exp2f(x); }

// async global->LDS, 16B per lane; LDS dest = wave-uniform base + lane*16
__device__ __forceinline__ void gl_lds16(const u16* g, u16* l){
  __builtin_amdgcn_global_load_lds(
      (const __attribute__((address_space(1))) unsigned int*)g,
      (__attribute__((address_space(3))) unsigned int*)l,
      16, 0, 0);
}

// ---------------------------------------------------------------------------
// One-time fp32->bf16 conversion of W_embed, X, W_adj, W1, W2, Wp,
// PLUS (fused) position-bias precompute (pre-scaled by log2e).
// ---------------------------------------------------------------------------
constexpr int WeN   = 12544 * 1280;   // 16,056,320
constexpr int XN    = 768 * 1280;     //    983,040
constexpr int WadjN = 256 * CNc;      //  3,211,264
constexpr int W1N   = 256 * 1280;     //    327,680
constexpr int W2N   = 128 * 256;      //     32,768
constexpr int WpN   = 64 * 64;        //      4,096
constexpr int CONVB = (WeN + XN + WadjN + W1N + W2N + WpN) / (256*8);   // 10066 exact
constexpr int BIASB = (2 * NHc * Ac * Nc + 255) / 256;                  // 601
__global__ __launch_bounds__(256) void conv_bias_kernel(const float* __restrict__ We,
                                                        const float* __restrict__ X,
                                                        const float* __restrict__ Wadj,
                                                        const float* __restrict__ W1,
                                                        const float* __restrict__ W2,
                                                        const float* __restrict__ Wp,
                                                        u16* __restrict__ WeB,
                                                        u16* __restrict__ XB,
                                                        u16* __restrict__ WadjB,
                                                        u16* __restrict__ W1B,
                                                        u16* __restrict__ W2B,
                                                        u16* __restrict__ WpB,
                                                        const float* __restrict__ an, const float* __restrict__ na,
                                                        const float* __restrict__ ah, const float* __restrict__ aw,
                                                        const float* __restrict__ ha, const float* __restrict__ wa,
                                                        float* __restrict__ pb, float* __restrict__ ab)
{
  if (blockIdx.x >= CONVB) {
    // ---- bias path (math identical; output scaled by LOG2E) ----
    constexpr float LOG2E = 1.4426950408889634f;
    const int total = NHc * Ac * Nc;   // 76832
    int idx = (blockIdx.x - CONVB) * 256 + threadIdx.x;
    if (idx >= 2 * total) return;
    const bool isab = idx >= total;
    const int r = isab ? idx - total : idx;
    const int h = r / (Ac * Nc);
    const int r2 = r % (Ac * Nc);
    int a, n;
    if (isab) { n = r2 / Ac; a = r2 % Ac; } else { a = r2 / Nc; n = r2 % Nc; }
    const int y = n / WINc, x = n % WINc;
    float sy = fminf(fmaxf(0.5f * y - 0.25f, 0.f), 6.f);
    float sx = fminf(fmaxf(0.5f * x - 0.25f, 0.f), 6.f);
    const int y0 = (int)sy, x0 = (int)sx;
    const float wy = sy - y0, wx = sx - x0;
    const int y1 = (y0 + 1 < 6) ? y0 + 1 : 6;
    const int x1 = (x0 + 1 < 6) ? x0 + 1 : 6;
    const float* src = (isab ? na : an) + (h * Ac + a) * 49;
    const float v00 = src[y0*7 + x0], v01 = src[y0*7 + x1];
    const float v10 = src[y1*7 + x0], v11 = src[y1*7 + x1];
    const float bi = (1.f - wy) * ((1.f - wx) * v00 + wx * v01)
                   + wy * ((1.f - wx) * v10 + wx * v11);
    if (!isab) pb[((size_t)h*Nc + n)*Ac + a] = (bi + ah[(h*Ac + a)*WINc + y] + aw[(h*Ac + a)*WINc + x]) * LOG2E;
    else       ab[((size_t)h*Ac + a)*Nc + n] = (bi + ha[(h*WINc + y)*Ac + a] + wa[(h*WINc + x)*Ac + a]) * LOG2E;
    return;
  }
  // ---- conv path ----
  const size_t idx = ((size_t)blockIdx.x * 256 + threadIdx.x) * 8;
  const float* src; u16* dst;
  size_t off = idx;
  if (off < (size_t)WeN)            { src = We + off;   dst = WeB + off; }
  else if ((off -= WeN) < XN)       { src = X + off;    dst = XB + off; }
  else if ((off -= XN) < WadjN)     { src = Wadj + off; dst = WadjB + off; }
  else if ((off -= WadjN) < W1N)    { src = W1 + off;   dst = W1B + off; }
  else if ((off -= W1N) < W2N)      { src = W2 + off;   dst = W2B + off; }
  else                              { off -= W2N; src = Wp + off; dst = WpB + off; }
  float v[8];
  *reinterpret_cast<float4*>(&v[0]) = *reinterpret_cast<const float4*>(src);
  *reinterpret_cast<float4*>(&v[4]) = *reinterpret_cast<const float4*>(src + 4);
  *reinterpret_cast<uint4*>(dst) = pack8(v);
}

// ---------------------------------------------------------------------------
// MERGED embed + mlp1 GEMM (same K=1280, same A=XB), m97 gload_lds staging.
// ---------------------------------------------------------------------------
__global__ __launch_bounds__(256) void gemm_embed_mlp1(const u16* __restrict__ XB,
                                                       const u16* __restrict__ WeB,
                                                       const u16* __restrict__ W1B,
                                                       const float* __restrict__ be,
                                                       const float* __restrict__ b1,
                                                       u16* __restrict__ xt,
                                                       u16* __restrict__ H)
{
  constexpr int KK = Dd;
  __shared__ u16 As[128 * 32];
  __shared__ u16 Bs[128 * 32];
  const int t = threadIdx.x;
  const bool mlp = blockIdx.x >= 98;
  const int n0 = (mlp ? (blockIdx.x - 98) : blockIdx.x) * 128;
  const int m0 = blockIdx.y * 128;
  const u16* Bmat = mlp ? W1B : WeB;
  const float* bias = mlp ? b1 : be;
  u16* Cmat = mlp ? H : xt;
  const int NN = mlp ? 256 : CNc;
  const int wave = t >> 6, lane = t & 63;
  const int wm = wave >> 1, wn = wave & 1;
  const int mi = lane & 15, quad = lane >> 4;

  v4f acc[4][4];
  #pragma unroll
  for (int a = 0; a < 4; ++a)
    #pragma unroll
    for (int b = 0; b < 4; ++b) acc[a][b] = (v4f){0.f, 0.f, 0.f, 0.f};

  const int rs = wave*32 + (lane >> 2);
  const int cs = (lane & 3) * 8;
  const u16* ga0 = XB + (size_t)(m0 + rs) * KK + cs;
  const u16* ga1 = XB + (size_t)(m0 + rs + 16) * KK + cs;
  const u16* gb0 = Bmat + (size_t)(n0 + rs) * KK + cs;
  const u16* gb1 = Bmat + (size_t)(n0 + rs + 16) * KK + cs;
  u16* la0 = &As[(wave*32)      * 32];
  u16* la1 = &As[(wave*32 + 16) * 32];
  u16* lb0 = &Bs[(wave*32)      * 32];
  u16* lb1 = &Bs[(wave*32 + 16) * 32];

  for (int kt = 0; kt < KK; kt += 32) {
    gl_lds16(ga0 + kt, la0);
    gl_lds16(ga1 + kt, la1);
    gl_lds16(gb0 + kt, lb0);
    gl_lds16(gb1 + kt, lb1);
    __syncthreads();

    v8s af[4], bf[4];
    #pragma unroll
    for (int mt = 0; mt < 4; ++mt)
      af[mt] = *reinterpret_cast<const v8s*>(&As[(wm*64 + mt*16 + mi)*32 + quad*8]);
    #pragma unroll
    for (int nt = 0; nt < 4; ++nt)
      bf[nt] = *reinterpret_cast<const v8s*>(&Bs[(wn*64 + nt*16 + mi)*32 + quad*8]);
    #pragma unroll
    for (int mt = 0; mt < 4; ++mt)
      #pragma unroll
      for (int nt = 0; nt < 4; ++nt)
        acc[mt][nt] = __builtin_amdgcn_mfma_f32_16x16x32_bf16(af[mt], bf[nt], acc[mt][nt], 0, 0, 0);
    __syncthreads();
  }

  #pragma unroll
  for (int nt = 0; nt < 4; ++nt) {
    const int col = n0 + wn*64 + nt*16 + mi;
    const float bc = bias[col];
    #pragma unroll
    for (int mt = 0; mt < 4; ++mt) {
      #pragma unroll
      for (int r = 0; r < 4; ++r) {
        const int row = m0 + wm*64 + mt*16 + quad*4 + r;
        float val = acc[mt][nt][r] + bc;
        if (mlp) val = tanhf(val);
        Cmat[(size_t)row * NN + col] = f2bb(val);
      }
    }
  }
}

// ---------------------------------------------------------------------------
// MERGED tail: blocks < B3c reduce_bias; blocks >= B3c mlp2.
// ---------------------------------------------------------------------------
__global__ __launch_bounds__(256) void tail_kernel(const float* __restrict__ part,
                                                   const float* __restrict__ badj,
                                                   float* __restrict__ outadj,
                                                   const u16* __restrict__ H,
                                                   const u16* __restrict__ W2B,
                                                   const float* __restrict__ b2,
                                                   float* __restrict__ outp)
{
  __shared__ u16 As[128 * 40];
  __shared__ u16 Bs[128 * 40];
  const int t = threadIdx.x;
  if (blockIdx.x < B3c) {
    const int idx = blockIdx.x * 256 + t;           // 768*256 exact
    const int n = idx & 255;
    float acc = badj[n];
    #pragma unroll
    for (int s = 0; s < 8; ++s) acc += part[(size_t)s * B3c * 256 + idx];
    outadj[idx] = acc;
    return;
  }
  const int m0 = (blockIdx.x - B3c) * 128;
  const int wave = t >> 6, lane = t & 63;
  const int wm = wave >> 1, wn = wave & 1;
  const int mi = lane & 15, quad = lane >> 4;
  const int srow = t >> 1, scol = (t & 1) * 16;

  v4f acc[4][4];
  #pragma unroll
  for (int a = 0; a < 4; ++a)
    #pragma unroll
    for (int b = 0; b < 4; ++b) acc[a][b] = (v4f){0.f, 0.f, 0.f, 0.f};

  for (int kt = 0; kt < 256; kt += 32) {
    const u16* ap = H + (size_t)(m0 + srow) * 256 + kt + scol;
    *reinterpret_cast<uint4*>(&As[srow*40 + scol])     = *reinterpret_cast<const uint4*>(ap);
    *reinterpret_cast<uint4*>(&As[srow*40 + scol + 8]) = *reinterpret_cast<const uint4*>(ap + 8);
    const u16* bp = W2B + (size_t)srow * 256 + kt + scol;
    *reinterpret_cast<uint4*>(&Bs[srow*40 + scol])     = *reinterpret_cast<const uint4*>(bp);
    *reinterpret_cast<uint4*>(&Bs[srow*40 + scol + 8]) = *reinterpret_cast<const uint4*>(bp + 8);
    __syncthreads();

    v8s af[4], bf[4];
    #pragma unroll
    for (int mt = 0; mt < 4; ++mt)
      af[mt] = *reinterpret_cast<const v8s*>(&As[(wm*64 + mt*16 + mi)*40 + quad*8]);
    #pragma unroll
    for (int nt = 0; nt < 4; ++nt)
      bf[nt] = *reinterpret_cast<const v8s*>(&Bs[(wn*64 + nt*16 + mi)*40 + quad*8]);
    #pragma unroll
    for (int mt = 0; mt < 4; ++mt)
      #pragma unroll
      for (int nt = 0; nt < 4; ++nt)
        acc[mt][nt] = __builtin_amdgcn_mfma_f32_16x16x32_bf16(af[mt], bf[nt], acc[mt][nt], 0, 0, 0);
    __syncthreads();
  }

  #pragma unroll
  for (int nt = 0; nt < 4; ++nt) {
    const int col = wn*64 + nt*16 + mi;   // 0..127
    const float bc = b2[col];
    #pragma unroll
    for (int mt = 0; mt < 4; ++mt) {
      #pragma unroll
      for (int r = 0; r < 4; ++r) {
        const int row = m0 + wm*64 + mt*16 + quad*4 + r;
        const int bi = row / 3, s = row - bi * 3;
        outp[(size_t)s * (Bn*128) + (size_t)bi * 128 + col] = acc[mt][nt][r] + bc;
      }
    }
  }
}

// ---------------------------------------------------------------------------
// qkv via MFMA — 3 segments LOOPED in one block (grid 588)
// ---------------------------------------------------------------------------
__global__ __launch_bounds__(256) void qkv_mfma(const u16* __restrict__ xt, const float* __restrict__ Wqkv,
                                                u16* __restrict__ qh, u16* __restrict__ kh, u16* __restrict__ vb)
{
  __shared__ u16 As[256 * 72];
  __shared__ u16 Bs[64 * 72];
  const int t = threadIdx.x;
  const int m0 = blockIdx.x * 256;
  const int wave = t >> 6, lane = t & 63;
  const int mi = lane & 15, quad = lane >> 4;

  {
    const int ar = t >> 2, ac = (t & 3) * 16;
    #pragma unroll
    for (int rb = 0; rb < 4; ++rb) {
      const int row = rb*64 + ar;
      const uint4* src = reinterpret_cast<const uint4*>(xt + ((size_t)(m0 + row))*64 + ac);
      *reinterpret_cast<uint4*>(&As[row*72 + ac])     = src[0];
      *reinterpret_cast<uint4*>(&As[row*72 + ac + 8]) = src[1];
    }
  }
  __syncthreads();   // As visible

  v8s af[2][4];      // seg-invariant A fragments
  #pragma unroll
  for (int ks = 0; ks < 2; ++ks)
    #pragma unroll
    for (int mt = 0; mt < 4; ++mt)
      af[ks][mt] = *reinterpret_cast<const v8s*>(&As[(wave*64 + mt*16 + mi)*72 + ks*32 + quad*8]);

  #pragma unroll 1
  for (int seg = 0; seg < 3; ++seg) {
    if (seg) __syncthreads();          // prior segment's Bs reads complete
    for (int i = t; i < Cc*Cc; i += 256) {
      const int j = i >> 6, c = i & 63;
      Bs[j*72 + c] = f2bb(Wqkv[(size_t)(seg*64 + j)*64 + c]);
    }
    __syncthreads();                   // Bs visible

    v4f acc[4][4];
    #pragma unroll
    for (int a = 0; a < 4; ++a)
      #pragma unroll
      for (int b = 0; b < 4; ++b) acc[a][b] = (v4f){0.f, 0.f, 0.f, 0.f};

    #pragma unroll
    for (int ks = 0; ks < 2; ++ks) {
      v8s bf[4];
      #pragma unroll
      for (int nt = 0; nt < 4; ++nt)
        bf[nt] = *reinterpret_cast<const v8s*>(&Bs[(nt*16 + mi)*72 + ks*32 + quad*8]);
      #pragma unroll
      for (int mt = 0; mt < 4; ++mt)
        #pragma unroll
        for (int nt = 0; nt < 4; ++nt)
          acc[mt][nt] = __builtin_amdgcn_mfma_f32_16x16x32_bf16(af[ks][mt], bf[nt], acc[mt][nt], 0, 0, 0);
    }

    u16* hm = (seg == 0) ? qh : kh;
    #pragma unroll
    for (int nt = 0; nt < 4; ++nt) {
      const int col = nt*16 + mi;
      const int h = col >> 3, d = col & 7;
      #pragma unroll
      for (int mt = 0; mt < 4; ++mt) {
        #pragma unroll
        for (int r = 0; r < 4; ++r) {
          const int row = m0 + wave*64 + mt*16 + quad*4 + r;
          const u16 val = f2bb(acc[mt][nt][r]);
          if (seg < 2) {
            const int b = row / Nc, n = row - b * Nc;
            hm[((size_t)(b*NHc + h)*Nc + n)*8 + d] = val;
          } else {
            vb[(size_t)row * 64 + col] = val;
          }
        }
      }
    }
  }
}

// ---------------------------------------------------------------------------
// fused agent attention (R14 version: hw-exp2 + XCD-coherent decode; ~111 µs)
// ---------------------------------------------------------------------------
__global__ __launch_bounds__(256) void attn_kernel(const u16* __restrict__ qh, const u16* __restrict__ kh,
                                                   const u16* __restrict__ v,
                                                   const float* __restrict__ pb, const float* __restrict__ ab,
                                                   u16* __restrict__ o)
{
  __shared__ float sU[Nc*10];        // union: sQ (Nc*8) then sPart (Nc*9 used)
  __shared__ float sK[Nc*8], sV[Nc*8];
  __shared__ float sAg[Ac*8], sAV[Ac*8];
  const int bhid = blockIdx.x;
  const int h = bhid / B3c, b = bhid - h * B3c;   // XCD-coherent decode
  const int bh = b * NHc + h;                     // data index (layout unchanged)
  const int t = threadIdx.x;
  const float scale2 = 0.3535533905932738f * 1.4426950408889634f;  // scale * log2(e)

  float qreg[8];
  if (t < Nc) {
    const size_t base = ((size_t)bh * Nc + t) * 8;
    unpack8(*reinterpret_cast<const uint4*>(qh + base), qreg);
    #pragma unroll
    for (int d = 0; d < 8; ++d) sU[t*8 + d] = qreg[d];   // sQ view
    unpack8(*reinterpret_cast<const uint4*>(kh + base), &sK[t*8]);
    unpack8(*reinterpret_cast<const uint4*>(v + ((size_t)b*Nc + t)*64 + h*8), &sV[t*8]);
  }
  __syncthreads();

  for (int i = t; i < Ac*8; i += 256) {
    const int a = i >> 3, d = i & 7;
    const int ay = a / 7, ax = a % 7;
    const int n00 = (ay * 2) * WINc + ax * 2;
    sAg[i] = 0.25f * (sU[n00*8+d] + sU[(n00+1)*8+d] + sU[(n00+WINc)*8+d] + sU[(n00+WINc+1)*8+d]);
  }
  __syncthreads();   // sQ reads done; sU becomes sPart

  // stage 1: thread t<196 -> quarter qd, agent a; 2-way unrolled
  if (t < Nc) {
    const int qd = t / Ac, a = t - qd * Ac;
    const int nb = qd * Ac;
    v2f g2[4];
    #pragma unroll
    for (int d2 = 0; d2 < 4; ++d2) g2[d2] = *reinterpret_cast<const v2f*>(&sAg[a*8 + d2*2]);
    const float* pbr = pb + ((size_t)h*Nc + nb)*Ac + a;   // step Ac per j
    float l0 = 0.f, l1 = 0.f;
    v2f avA[4] = {}, avB[4] = {};
    for (int j = 0; j < 48; j += 2) {
      const v2f* k0 = reinterpret_cast<const v2f*>(&sK[(nb + j)*8]);
      const v2f* k1 = reinterpret_cast<const v2f*>(&sK[(nb + j + 1)*8]);
      v2f sa = (g2[0]*k0[0] + g2[1]*k0[1]) + (g2[2]*k0[2] + g2[3]*k0[3]);
      v2f sb = (g2[0]*k1[0] + g2[1]*k1[1]) + (g2[2]*k1[2] + g2[3]*k1[3]);
      const float e0 = hexp2(fmaf(sa.x + sa.y, scale2, pbr[j*Ac]));
      const float e1 = hexp2(fmaf(sb.x + sb.y, scale2, pbr[(j+1)*Ac]));
      l0 += e0; l1 += e1;
      const v2f* v0 = reinterpret_cast<const v2f*>(&sV[(nb + j)*8]);
      const v2f* v1 = reinterpret_cast<const v2f*>(&sV[(nb + j + 1)*8]);
      const v2f e02 = {e0, e0}, e12 = {e1, e1};
      #pragma unroll
      for (int d2 = 0; d2 < 4; ++d2) { avA[d2] += e02 * v0[d2]; avB[d2] += e12 * v1[d2]; }
    }
    { // tail j = 48
      const v2f* k0 = reinterpret_cast<const v2f*>(&sK[(nb + 48)*8]);
      v2f sa = (g2[0]*k0[0] + g2[1]*k0[1]) + (g2[2]*k0[2] + g2[3]*k0[3]);
      const float e0 = hexp2(fmaf(sa.x + sa.y, scale2, pbr[48*Ac]));
      l0 += e0;
      const v2f* v0 = reinterpret_cast<const v2f*>(&sV[(nb + 48)*8]);
      const v2f e02 = {e0, e0};
      #pragma unroll
      for (int d2 = 0; d2 < 4; ++d2) avA[d2] += e02 * v0[d2];
    }
    float* pp = &sU[t*9];            // sPart view
    pp[0] = l0 + l1;
    #pragma unroll
    for (int d2 = 0; d2 < 4; ++d2) {
      const v2f m = avA[d2] + avB[d2];
      pp[1+d2*2] = m.x; pp[2+d2*2] = m.y;
    }
  }
  __syncthreads();

  if (t < Ac) {
    float L = 0.f, av[8] = {};
    #pragma unroll
    for (int p = 0; p < 4; ++p) {
      const float* pp = &sU[(p*Ac + t)*9];
      L += pp[0];
      #pragma unroll
      for (int d = 0; d < 8; ++d) av[d] += pp[1+d];
    }
    const float inv = 1.f / L;
    #pragma unroll
    for (int d = 0; d < 8; ++d) sAV[t*8 + d] = av[d] * inv;
  }
  __syncthreads();

  // stage 2: thread = token n; 2-way unrolled over agents
  if (t < Nc) {
    v2f q2[4];
    #pragma unroll
    for (int d2 = 0; d2 < 4; ++d2) q2[d2] = (v2f){qreg[d2*2], qreg[d2*2+1]};
    const float* abr = ab + (size_t)h*Ac*Nc + t;          // step Nc per a
    float l0 = 0.f, l1 = 0.f;
    v2f oA[4] = {}, oB[4] = {};
    for (int a = 0; a < 48; a += 2) {
      const v2f* g0 = reinterpret_cast<const v2f*>(&sAg[a*8]);
      const v2f* g1 = reinterpret_cast<const v2f*>(&sAg[(a+1)*8]);
      v2f sa = (q2[0]*g0[0] + q2[1]*g0[1]) + (q2[2]*g0[2] + q2[3]*g0[3]);
      v2f sb = (q2[0]*g1[0] + q2[1]*g1[1]) + (q2[2]*g1[2] + q2[3]*g1[3]);
      const float e0 = hexp2(fmaf(sa.x + sa.y, scale2, abr[a*Nc]));
      const float e1 = hexp2(fmaf(sb.x + sb.y, scale2, abr[(a+1)*Nc]));
      l0 += e0; l1 += e1;
      const v2f* a0 = reinterpret_cast<const v2f*>(&sAV[a*8]);
      const v2f* a1 = reinterpret_cast<const v2f*>(&sAV[(a+1)*8]);
      const v2f e02 = {e0, e0}, e12 = {e1, e1};
      #pragma unroll
      for (int d2 = 0; d2 < 4; ++d2) { oA[d2] += e02 * a0[d2]; oB[d2] += e12 * a1[d2]; }
    }
    { // tail a = 48
      const v2f* g0 = reinterpret_cast<const v2f*>(&sAg[48*8]);
      v2f sa = (q2[0]*g0[0] + q2[1]*g0[1]) + (q2[2]*g0[2] + q2[3]*g0[3]);
      const float e0 = hexp2(fmaf(sa.x + sa.y, scale2, abr[48*Nc]));
      l0 += e0;
      const v2f* a0 = reinterpret_cast<const v2f*>(&sAV[48*8]);
      const v2f e02 = {e0, e0};
      #pragma unroll
      for (int d2 = 0; d2 < 4; ++d2) oA[d2] += e02 * a0[d2];
    }
    const float inv = 1.f / (l0 + l1);
    float o8[8];
    #pragma unroll
    for (int d2 = 0; d2 < 4; ++d2) {
      const v2f m = oA[d2] + oB[d2];
      o8[d2*2] = m.x * inv; o8[d2*2+1] = m.y * inv;
    }
    *reinterpret_cast<uint4*>(&o[((size_t)b*Nc + t)*64 + h*8]) = pack8(o8);
  }
}

// ---------------------------------------------------------------------------
// FUSED dwc + proj v2 (R8 retry with root cause fixed):
//   - dwc phase = R9's VECTORIZED dwc (8 independent ds_read_b128/iter, not
//     441 serial scalar chains) -> tolerates 2 blocks/CU.
//   - dwc output written to sU [208][72] bf16 (same f2bb point as before).
//   - proj B-fragments hoisted to 8 registers loaded ONCE from L2-resident
//     WpB (preconverted bf16) -> no sW LDS. LDS = 56 KB -> 2 blocks/CU.
//   - sU rows 196..207 left uninitialized: they only feed C rows >=196,
//     which are never stored.
//   Removes proj launch + U's 38.6 MB HBM round-trip. o -> oproj in-place is
//   safe: o fully consumed into sU before the barrier preceding stores.
// ---------------------------------------------------------------------------
__global__ __launch_bounds__(256) void dwc_proj_kernel(const u16* __restrict__ o, const u16* __restrict__ v,
                                                       const float* __restrict__ dwc_w, const float* __restrict__ dwc_b,
                                                       const u16* __restrict__ WpB, const float* __restrict__ bp,
                                                       u16* __restrict__ oproj)
{
  __shared__ u16 sV[Nc*Cc];        // 25088 B
  __shared__ float sWw[9*64];      //  2304 B
  __shared__ u16 sU[208*72];       // 29952 B  (total 57344 B = 56 KB)
  const int b = blockIdx.x, t = threadIdx.x;
  const int wave = t >> 6, lane = t & 63;
  const int mi = lane & 15, quad = lane >> 4;

  const uint2* vsrc = reinterpret_cast<const uint2*>(v + (size_t)b * CNc);
  uint2* sV2 = reinterpret_cast<uint2*>(sV);
  for (int i = t; i < CNc/4; i += 256) sV2[i] = vsrc[i];
  for (int i = t; i < 9*64; i += 256) {
    const int k = i >> 6, c = i & 63;
    sWw[i] = dwc_w[c*9 + k];
  }
  __syncthreads();

  const int c0 = (t & 7) * 8;      // fixed channel block per thread
  float wreg[9][8], breg[8];
  #pragma unroll
  for (int k = 0; k < 9; ++k) {
    *reinterpret_cast<float4*>(&wreg[k][0]) = *reinterpret_cast<const float4*>(&sWw[k*64 + c0]);
    *reinterpret_cast<float4*>(&wreg[k][4]) = *reinterpret_cast<const float4*>(&sWw[k*64 + c0 + 4]);
  }
  *reinterpret_cast<float4*>(&breg[0]) = *reinterpret_cast<const float4*>(dwc_b + c0);
  *reinterpret_cast<float4*>(&breg[4]) = *reinterpret_cast<const float4*>(dwc_b + c0 + 4);

  // proj B-fragments (block-invariant): 8 x 16B from L2-resident WpB
  v8s bfr[2][4];
  #pragma unroll
  for (int ks = 0; ks < 2; ++ks)
    #pragma unroll
    for (int nt = 0; nt < 4; ++nt)
      bfr[ks][nt] = *reinterpret_cast<const v8s*>(WpB + (size_t)(nt*16 + mi)*64 + ks*32 + quad*8);

  // ---- dwc phase (R9 math, bit-identical; output -> sU) ----
  const u16* ob = o + (size_t)b * CNc;
  for (int i = t; i < CNc/8; i += 256) {     // 1568 items of 8 channels
    const int n = i >> 3;
    const int y = n / WINc, x = n % WINc;
    float acc[8], vv[8];
    unpack8(*reinterpret_cast<const uint4*>(ob + (size_t)i*8), acc);   // residual
    #pragma unroll
    for (int j = 0; j < 8; ++j) acc[j] += breg[j];                     // + bias
    #pragma unroll
    for (int ky = 0; ky < 3; ++ky) {
      const int yy = y + ky - 1;
      if (yy < 0 || yy >= WINc) continue;
      #pragma unroll
      for (int kx = 0; kx < 3; ++kx) {
        const int xx = x + kx - 1;
        if (xx < 0 || xx >= WINc) continue;
        const int k = ky*3 + kx;
        unpack8(*reinterpret_cast<const uint4*>(&sV[(yy*WINc + xx)*Cc + c0]), vv);
        #pragma unroll
        for (int j = 0; j < 8; ++j) acc[j] = fmaf(wreg[k][j], vv[j], acc[j]);
      }
    }
    *reinterpret_cast<uint4*>(&sU[n*72 + c0]) = pack8(acc);
  }
  __syncthreads();

  // ---- proj phase: oproj = U·Wp^T + bp (A from sU, B in regs) ----
  u16* op = oproj + (size_t)b * CNc;
  for (int mt = wave; mt < 13; mt += 4) {
    v4f acc[4];
    #pragma unroll
    for (int nt = 0; nt < 4; ++nt) acc[nt] = (v4f){0.f, 0.f, 0.f, 0.f};
    #pragma unroll
    for (int ks = 0; ks < 2; ++ks) {
      const v8s af = *reinterpret_cast<const v8s*>(&sU[(mt*16 + mi)*72 + ks*32 + quad*8]);
      #pragma unroll
      for (int nt = 0; nt < 4; ++nt)
        acc[nt] = __builtin_amdgcn_mfma_f32_16x16x32_bf16(af, bfr[ks][nt], acc[nt], 0, 0, 0);
    }
    #pragma unroll
    for (int nt = 0; nt < 4; ++nt) {
      const int col = nt*16 + mi;
      const float bc = bp[col];
      #pragma unroll
      for (int r = 0; r < 4; ++r) {
        const int row = mt*16 + quad*4 + r;
        if (row < Nc)
          op[(size_t)row * 64 + col] = f2bb(acc[nt][r] + bc);
      }
    }
  }
}

// ---------------------------------------------------------------------------
// adjacency GEMM via MFMA, split-K(8), 128x128 tiles + global_load_lds
// (unchanged, passing)
// ---------------------------------------------------------------------------
__global__ __launch_bounds__(256) void gemm_adj_mfma(const u16* __restrict__ Amat,
                                                     const u16* __restrict__ BmatB,
                                                     float* __restrict__ part)
{
  constexpr int K = CNc, Kc = CNc/8;   // 1568 = 49*32
  __shared__ u16 As[128 * 32];
  __shared__ u16 Bs[128 * 32];
  const int t = threadIdx.x;
  const int n0 = blockIdx.x * 128, m0 = blockIdx.y * 128;
  const int kbeg = blockIdx.z * Kc;
  const int wave = t >> 6, lane = t & 63;
  const int wm = wave >> 1, wn = wave & 1;
  const int mi = lane & 15, quad = lane >> 4;

  v4f acc[4][4];
  #pragma unroll
  for (int a = 0; a < 4; ++a)
    #pragma unroll
    for (int b = 0; b < 4; ++b) acc[a][b] = (v4f){0.f, 0.f, 0.f, 0.f};

  const int rs = wave*32 + (lane >> 2);
  const int cs = (lane & 3) * 8;
  const u16* ga0 = Amat + (size_t)(m0 + rs) * K + kbeg + cs;
  const u16* ga1 = Amat + (size_t)(m0 + rs + 16) * K + kbeg + cs;
  const u16* gb0 = BmatB + (size_t)(n0 + rs) * K + kbeg + cs;
  const u16* gb1 = BmatB + (size_t)(n0 + rs + 16) * K + kbeg + cs;
  u16* la0 = &As[(wave*32)      * 32];
  u16* la1 = &As[(wave*32 + 16) * 32];
  u16* lb0 = &Bs[(wave*32)      * 32];
  u16* lb1 = &Bs[(wave*32 + 16) * 32];

  for (int kt = 0; kt < Kc; kt += 32) {
    gl_lds16(ga0 + kt, la0);
    gl_lds16(ga1 + kt, la1);
    gl_lds16(gb0 + kt, lb0);
    gl_lds16(gb1 + kt, lb1);
    __syncthreads();

    v8s af[4], bf[4];
    #pragma unroll
    for (int mt = 0; mt < 4; ++mt)
      af[mt] = *reinterpret_cast<const v8s*>(&As[(wm*64 + mt*16 + mi)*32 + quad*8]);
    #pragma unroll
    for (int nt = 0; nt < 4; ++nt)
      bf[nt] = *reinterpret_cast<const v8s*>(&Bs[(wn*64 + nt*16 + mi)*32 + quad*8]);
    #pragma unroll
    for (int mt = 0; mt < 4; ++mt)
      #pragma unroll
      for (int nt = 0; nt < 4; ++nt)
        acc[mt][nt] = __builtin_amdgcn_mfma_f32_16x16x32_bf16(af[mt], bf[nt], acc[mt][nt], 0, 0, 0);
    __syncthreads();
  }

  const size_t zoff = (size_t)blockIdx.z * B3c * 256;
  #pragma unroll
  for (int nt = 0; nt < 4; ++nt) {
    const int col = n0 + wn*64 + nt*16 + mi;
    #pragma unroll
    for (int mt = 0; mt < 4; ++mt) {
      #pragma unroll
      for (int r = 0; r < 4; ++r) {
        const int row = m0 + wm*64 + mt*16 + quad*4 + r;
        part[zoff + (size_t)row * 256 + col] = acc[mt][nt][r];
      }
    }
  }
}

// ---------------------------------------------------------------------------
extern "C" void kernel_launch(void* const* d_in, const int* in_sizes, int n_in,
                              void* d_out, int out_size, void* d_ws, size_t ws_size,
                              hipStream_t stream)
{
  auto in = [&](int i){ return reinterpret_cast<const float*>(d_in[i]); };
  const float *X = in(0), *We = in(1), *be = in(2), *Wq = in(3), *Wp = in(4), *bp = in(5),
              *dww = in(6), *dwb = in(7), *anb = in(8), *nab = in(9), *ahb = in(10), *awb = in(11),
              *hab = in(12), *wab = in(13), *Wadj = in(14), *badj = in(15),
              *W1 = in(16), *b1 = in(17), *W2 = in(18), *b2 = in(19);
  float* out = reinterpret_cast<float*>(d_out);
  char* w = reinterpret_cast<char*>(d_ws);

  const size_t TOK = (size_t)B3c * CNc;          // 9,633,792 elements
  u16* xt = reinterpret_cast<u16*>(w);            // slot0: xt -> o -> oproj (in-place via dwc_proj)
  u16* qh = reinterpret_cast<u16*>(w + TOK*2);    // slot1: We_bf[0:] -> q head-major
  u16* kh = reinterpret_cast<u16*>(w + TOK*4);    // slot2: We_bf[..] -> k head-major -> part
  u16* vb = reinterpret_cast<u16*>(w + TOK*6);    // slot3: v token-major
  float* pb = reinterpret_cast<float*>(w + TOK*8);
  float* ab = pb + NHc*Ac*Nc;
  u16* WadjB = reinterpret_cast<u16*>(ab + NHc*Ac*Nc);   // 6.4 MB, persistent
  u16* XB  = WadjB + WadjN;                       // 2.0 MB, persistent (spare region)
  u16* W1B = XB + XN;                             // 0.66 MB, persistent
  u16* W2B = W1B + W1N;                           // 64 KB, persistent
  u16* WpB = W2B + W2N;                           // 8 KB, persistent
  u16* H   = WpB + WpN;                           // 0.39 MB, persistent
  u16* WeB = qh;                                  // 32.1 MB spans slot1+slot2 (38.5 MB)
  float* part = reinterpret_cast<float*>(kh);     // alias: kh dead after attn
  // total ws use: ~87.2 MB (<= 93.6 MB proven in R3)

  conv_bias_kernel<<<dim3(CONVB + BIASB), 256, 0, stream>>>(
      We, X, Wadj, W1, W2, Wp, WeB, XB, WadjB, W1B, W2B, WpB,
      anb, nab, ahb, awb, hab, wab, pb, ab);
  gemm_embed_mlp1<<<dim3(100, B3c/128), 256, 0, stream>>>(XB, WeB, W1B, be, b1, xt, H);
  qkv_mfma<<<dim3((B3c*Nc)/256), 256, 0, stream>>>(xt, Wq, qh, kh, vb);
  attn_kernel<<<dim3(B3c*NHc), 256, 0, stream>>>(qh, kh, vb, pb, ab, xt /*o*/);
  dwc_proj_kernel<<<dim3(B3c), 256, 0, stream>>>(xt /*o*/, vb, dww, dwb, WpB, bp, xt /*oproj*/);
  gemm_adj_mfma<<<dim3(256/128, B3c/128, 8), 256, 0, stream>>>(xt /*oproj*/, WadjB, part);
  tail_kernel<<<dim3(B3c + B3c/128), 256, 0, stream>>>(part, badj, out + 3*Bn*128, H, W2B, b2, out);
}